// Round 11
// baseline (151.657 us; speedup 1.0000x reference)
//
#include <hip/hip_runtime.h>
#include <hip/hip_bf16.h>

#define T_ 1024
#define N_ 8
#define D_ 1024
#define H_ 16
#define HD_ 64

typedef __attribute__((ext_vector_type(8))) short bf16x8;
typedef __attribute__((ext_vector_type(4))) float f32x4;
typedef __attribute__((ext_vector_type(16))) float f32x16;
typedef __attribute__((ext_vector_type(4))) int i32x4;
typedef __attribute__((ext_vector_type(2))) int i32x2;
typedef unsigned short u16;
typedef unsigned int u32;

__device__ __forceinline__ float bf2f(u16 u){
  union { float f; unsigned int i; } v; v.i = ((unsigned int)u) << 16; return v.f;
}
__device__ __forceinline__ u16 f2bf(float f){
  union { float f; unsigned int i; } v; v.f = f;
  unsigned int r = v.i + 0x7FFFu + ((v.i >> 16) & 1u);
  return (u16)(r >> 16);
}
__device__ __forceinline__ u16 f2bf_fast(float f){
  __hip_bfloat16 h = __float2bfloat16(f);   // RNE; compiler packs pairs into v_cvt_pk_bf16_f32
  return *reinterpret_cast<u16*>(&h);
}
// raw v_exp_f32: args are well inside normal range (p<=e^15), skip libm fixup tail
__device__ __forceinline__ float exp2_raw(float x){
  float r;
  asm("v_exp_f32 %0, %1" : "=v"(r) : "v"(x));
  return r;
}
// async global->LDS, 16B per lane, dest = wave-uniform base + lane*16
__device__ __forceinline__ void gl_lds16(const u16* g, u16* l){
  __builtin_amdgcn_global_load_lds(
      (const __attribute__((address_space(1))) unsigned int*)g,
      (__attribute__((address_space(3))) unsigned int*)(unsigned int)(unsigned long long)l,
      16, 0, 0);
}

// ---------------- transpose+cast Wq (D x D) -> Wqt[n][m] bf16 ----------------
__global__ __launch_bounds__(256) void k_wqt(const float* __restrict__ Wq, u16* __restrict__ Wqt){
  __shared__ float tld[64][65];
  int m0 = blockIdx.x * 64, n0 = blockIdx.y * 64;
  int col = threadIdx.x & 63, rq = threadIdx.x >> 6;
  #pragma unroll
  for (int p = 0; p < 16; ++p){
    int row = rq * 16 + p;
    tld[row][col] = Wq[(size_t)(m0 + row) * D_ + n0 + col];
  }
  __syncthreads();
  #pragma unroll
  for (int p = 0; p < 16; ++p){
    int row = rq * 16 + p;
    Wqt[(size_t)(n0 + row) * D_ + m0 + col] = f2bf(tld[col][row]);
  }
}

// ---------------- Bp[sp][h][d][e] partials of sum_m qw[m,h,e]*vw[m,h,d] (MFMA split-K) ----------------
__global__ __launch_bounds__(256) void k_bmatp(const float* __restrict__ qw, const float* __restrict__ vw,
                                               float* __restrict__ Bp){
  int h = (int)blockIdx.x >> 3, sp = (int)blockIdx.x & 7;
  int tid = threadIdx.x, lane = tid & 63, w = tid >> 6;
  int g = lane >> 4, c = lane & 15;
  __shared__ u16 Qt[64 * 72];  // [e][m] transposed, bf16
  __shared__ u16 Vt[64 * 72];  // [d][m]
  f32x4 zero = {0.f, 0.f, 0.f, 0.f};
  f32x4 acc[4];
  #pragma unroll
  for (int eb = 0; eb < 4; ++eb) acc[eb] = zero;
  int m = tid >> 2, cg = tid & 3;
  for (int mt = sp * 128; mt < sp * 128 + 128; mt += 64){
    __syncthreads();
    #pragma unroll
    for (int q = 0; q < 4; ++q){
      int e0 = cg * 16 + q * 4;
      f32x4 vq = *(const f32x4*)(qw + (size_t)(mt + m) * D_ + h * 64 + e0);
      f32x4 vv = *(const f32x4*)(vw + (size_t)(mt + m) * D_ + h * 64 + e0);
      #pragma unroll
      for (int j = 0; j < 4; ++j){
        Qt[(e0 + j) * 72 + m] = f2bf_fast(vq[j]);
        Vt[(e0 + j) * 72 + m] = f2bf_fast(vv[j]);
      }
    }
    __syncthreads();
    #pragma unroll
    for (int kk = 0; kk < 2; ++kk){
      bf16x8 av = *(const bf16x8*)&Vt[(w * 16 + c) * 72 + kk * 32 + g * 8];
      #pragma unroll
      for (int eb = 0; eb < 4; ++eb){
        bf16x8 bq = *(const bf16x8*)&Qt[(eb * 16 + c) * 72 + kk * 32 + g * 8];
        acc[eb] = __builtin_amdgcn_mfma_f32_16x16x32_bf16(av, bq, acc[eb], 0, 0, 0);
      }
    }
  }
  #pragma unroll
  for (int eb = 0; eb < 4; ++eb)
    #pragma unroll
    for (int r = 0; r < 4; ++r){
      int d = w * 16 + g * 4 + r, e = eb * 16 + c;
      Bp[(((size_t)sp * 16 + h) * 64 + d) * 64 + e] = acc[eb][r];
    }
}

// ---------------- reduce 8 partials -> Bt bf16 ----------------
__global__ __launch_bounds__(256) void k_bred(const float* __restrict__ Bp, u16* __restrict__ Bt){
  int i = blockIdx.x * 256 + threadIdx.x;   // 65536 total
  float s = 0.f;
  #pragma unroll
  for (int j = 0; j < 8; ++j) s += Bp[(size_t)j * 65536 + i];
  Bt[i] = f2bf(s * 0.125f);
}

// swizzled u16-index within a [rows][64] u16 LDS tile: XOR byte-bits 4-6 with row&7
__device__ __forceinline__ int swz(int row, int colbyte){
  return row * 64 + (((colbyte) ^ ((row & 7) << 4)) >> 1);
}

// ---------------- 128x128 bf16 MFMA GEMM, A[MxK] @ B^T (B given [N][K]) ----------------
template<int A_F32, int B_F32, int EPI>
__global__ __launch_bounds__(256) void k_gemm(const void* __restrict__ A_, const void* __restrict__ B_,
                                              void* __restrict__ Cv, const float* __restrict__ bias,
                                              int M, int N, int K){
  int nbn = N >> 7;
  int ii = (int)blockIdx.x;
  int sw = (ii & 7) * 64 + (ii >> 3);      // XCD-contiguous chunks (512 = 8*64 blocks)
  int bm = sw / nbn, bn = sw % nbn;
  int tid = threadIdx.x, lane = tid & 63, wid = tid >> 6;
  int wr = wid >> 1, wc = wid & 1, g = lane >> 4, c = lane & 15;
  __shared__ u16 As[128 * 64];
  __shared__ u16 Bs[128 * 64];
  f32x4 zero = {0.f, 0.f, 0.f, 0.f};
  f32x4 acc[4][4];
  #pragma unroll
  for (int m = 0; m < 4; ++m)
    #pragma unroll
    for (int n = 0; n < 4; ++n) acc[m][n] = zero;
  for (int kt = 0; kt < K; kt += 64){
    __syncthreads();
    #pragma unroll
    for (int p = 0; p < 4; ++p){
      int ci = tid + p * 256;
      int row = ci >> 3, c8 = ci & 7;
      int dst = swz(row, c8 * 16);
      if (A_F32){
        const float* A = (const float*)A_;
        const float* src = A + (size_t)(bm * 128 + row) * K + kt + c8 * 8;
        f32x4 v0 = *(const f32x4*)src;
        f32x4 v1 = *(const f32x4*)(src + 4);
        union { u16 u[8]; i32x4 v; } pk;
        #pragma unroll
        for (int j = 0; j < 4; ++j){ pk.u[j] = f2bf_fast(v0[j]); pk.u[4 + j] = f2bf_fast(v1[j]); }
        *(i32x4*)&As[dst] = pk.v;
      } else {
        const u16* A = (const u16*)A_;
        *(i32x4*)&As[dst] = *(const i32x4*)(A + (size_t)(bm * 128 + row) * K + kt + c8 * 8);
      }
      if (B_F32){
        const float* B = (const float*)B_;
        const float* src = B + (size_t)(bn * 128 + row) * K + kt + c8 * 8;
        f32x4 v0 = *(const f32x4*)src;
        f32x4 v1 = *(const f32x4*)(src + 4);
        union { u16 u[8]; i32x4 v; } pk;
        #pragma unroll
        for (int j = 0; j < 4; ++j){ pk.u[j] = f2bf_fast(v0[j]); pk.u[4 + j] = f2bf_fast(v1[j]); }
        *(i32x4*)&Bs[dst] = pk.v;
      } else {
        const u16* B = (const u16*)B_;
        *(i32x4*)&Bs[dst] = *(const i32x4*)(B + (size_t)(bn * 128 + row) * K + kt + c8 * 8);
      }
    }
    __syncthreads();
    #pragma unroll
    for (int kk = 0; kk < 2; ++kk){
      bf16x8 af[4], bfr[4];
      #pragma unroll
      for (int m = 0; m < 4; ++m){
        int row = wr * 64 + m * 16 + c;
        af[m] = *(const bf16x8*)&As[swz(row, kk * 64 + g * 16)];
      }
      #pragma unroll
      for (int n = 0; n < 4; ++n){
        int row = wc * 64 + n * 16 + c;
        bfr[n] = *(const bf16x8*)&Bs[swz(row, kk * 64 + g * 16)];
      }
      #pragma unroll
      for (int m = 0; m < 4; ++m)
        #pragma unroll
        for (int n = 0; n < 4; ++n)
          acc[m][n] = __builtin_amdgcn_mfma_f32_16x16x32_bf16(af[m], bfr[n], acc[m][n], 0, 0, 0);
    }
  }
  #pragma unroll
  for (int m = 0; m < 4; ++m)
    #pragma unroll
    for (int n = 0; n < 4; ++n)
      #pragma unroll
      for (int r = 0; r < 4; ++r){
        int row = bm * 128 + wr * 64 + m * 16 + g * 4 + r;
        int col = bn * 128 + wc * 64 + n * 16 + c;
        float v = acc[m][n][r];
        if (EPI == 0){
          int t = row >> 3, b = row & 7, hh = col >> 6, dd = col & 63;
          ((u16*)Cv)[(((size_t)(b * H_ + hh)) * T_ + t) * HD_ + dd] = f2bf(v);
        } else {
          ((float*)Cv)[(size_t)row * N + col] = v + bias[col];
        }
      }
}

// ---------------- u^T = B_h^T q^T per (bh, 64-t tile); also scaled q_sq. 1 wave. ----------------
__global__ __launch_bounds__(64) void k_u(const u16* __restrict__ qb, const u16* __restrict__ Bt,
                                          u16* __restrict__ ubt, float* __restrict__ qsq){
  int bh = blockIdx.x >> 4, tt = blockIdx.x & 15;
  int h = bh & 15, t0 = tt * 64;
  int lane = threadIdx.x, g = lane >> 4, c = lane & 15;
  const float QS_SCALE = 0.125f * 1.44269504088896340736f;
  bf16x8 af[4][2], bq[4][2];
  #pragma unroll
  for (int mf = 0; mf < 4; ++mf)
    #pragma unroll
    for (int kk = 0; kk < 2; ++kk)
      af[mf][kk] = *(const bf16x8*)(Bt + ((size_t)(h * 64 + mf * 16 + c)) * 64 + kk * 32 + g * 8);
  #pragma unroll
  for (int nf = 0; nf < 4; ++nf)
    #pragma unroll
    for (int kk = 0; kk < 2; ++kk)
      bq[nf][kk] = *(const bf16x8*)(qb + ((size_t)(bh * 1024 + t0 + nf * 16 + c)) * 64 + kk * 32 + g * 8);
  // q_sq from the same bf16 q; prescaled by 0.125*log2(e)
  #pragma unroll
  for (int nf = 0; nf < 4; ++nf){
    float ss = 0.f;
    #pragma unroll
    for (int kk = 0; kk < 2; ++kk)
      #pragma unroll
      for (int j = 0; j < 8; ++j){ float f = bf2f((u16)bq[nf][kk][j]); ss = fmaf(f, f, ss); }
    ss += __shfl_xor(ss, 16);
    ss += __shfl_xor(ss, 32);
    if (lane < 16) qsq[(size_t)bh * 1024 + t0 + nf * 16 + lane] = ss * QS_SCALE;
  }
  f32x4 zero = {0.f, 0.f, 0.f, 0.f};
  f32x4 acc[4][4];
  #pragma unroll
  for (int mf = 0; mf < 4; ++mf)
    #pragma unroll
    for (int nf = 0; nf < 4; ++nf) acc[mf][nf] = zero;
  #pragma unroll
  for (int kk = 0; kk < 2; ++kk)
    #pragma unroll
    for (int mf = 0; mf < 4; ++mf)
      #pragma unroll
      for (int nf = 0; nf < 4; ++nf)
        acc[mf][nf] = __builtin_amdgcn_mfma_f32_16x16x32_bf16(af[mf][kk], bq[nf][kk], acc[mf][nf], 0, 0, 0);
  #pragma unroll
  for (int mf = 0; mf < 4; ++mf)
    #pragma unroll
    for (int nf = 0; nf < 4; ++nf)
      #pragma unroll
      for (int r = 0; r < 4; ++r)
        ubt[((size_t)(bh * 64 + mf * 16 + g * 4 + r)) * 1024 + t0 + nf * 16 + c] = f2bf(acc[mf][nf][r]);
}

// ---------------- L2 attention: TBLK=128, software-pipelined PV (one phase behind QK) ----------------
// Phase st: stage(st+1) -> PV(st-1) [W regs from last phase, U from LDS] -> QK(st)
// -> SM(st) -> barrier. PV and QK are independent MFMA chains that fill the pipe;
// SM VALU overlaps the in-flight stage loads. K double-buffered (read same phase),
// U triple-buffered (read one phase later). LDS = 2*8K + 3*8K = 40 KB -> 4 blocks/CU.
// qsq read from L2 (64 KB/XCD working set). Math identical to rounds 7-10.
__global__ __launch_bounds__(256, 4) void k_attn(const u16* __restrict__ qb, const u16* __restrict__ ubt,
                                                 const float* __restrict__ qsq, u16* __restrict__ obm){
  int i = (int)blockIdx.x;
  // XCD grouping: XCD (i&7) owns bh in [16*(i&7), ...+16), all 8 t-tiles.
  int bh = ((i & 7) << 4) + (i >> 6);
  int tt = (i >> 3) & 7;
  int b = bh >> 4, h = bh & 15;
  int tid = threadIdx.x, w = tid >> 6, lane = tid & 63;
  int lo = lane & 31, hi = lane >> 5;
  __shared__ u16 Kl[2][64 * 64];
  __shared__ u16 Ul[3][64 * 64];
  const float C1 = 0.25f * 1.44269504088896340736f;
  int t0 = tt * 128 + w * 32;
  const u16* qbh = qb + (size_t)bh * 65536;    // [t][64]
  const u16* ubh = ubt + (size_t)bh * 65536;   // [e][1024]
  const float* qsb = qsq + (size_t)bh * 1024;
  // Q B-fragment (col=t=lo, k=d): 4 K=16 slices
  bf16x8 qB[4];
  #pragma unroll
  for (int kd = 0; kd < 4; ++kd)
    qB[kd] = *(const bf16x8*)(qbh + (t0 + lo) * 64 + kd * 16 + hi * 8);
  f32x16 o0 = {0,0,0,0,0,0,0,0,0,0,0,0,0,0,0,0};
  f32x16 o1 = {0,0,0,0,0,0,0,0,0,0,0,0,0,0,0,0};
  const f32x16 zero16 = {0,0,0,0,0,0,0,0,0,0,0,0,0,0,0,0};
  float l_c = 0.f;
  u32 W[16];
  // gload slots: per wave 2 calls per operand; slot=(w*2+j)*64+lane -> row=slot>>3, c8=slot&7
  int slot0 = (w * 2 + 0) * 64 + lane, slot1 = (w * 2 + 1) * 64 + lane;
  int r0 = slot0 >> 3, sc0 = ((slot0 & 7) ^ (r0 & 7)) * 8;   // pre-swizzled source chunk
  int r1 = slot1 >> 3, sc1 = ((slot1 & 7) ^ (r1 & 7)) * 8;
  int d0 = (w * 2 + 0) * 512, d1 = (w * 2 + 1) * 512;
  // prologue: stage tile 0 into K buf0 / U buf0
  gl_lds16(qbh + r0 * 64 + sc0, &Kl[0][d0]);
  gl_lds16(qbh + r1 * 64 + sc1, &Kl[0][d1]);
  gl_lds16(ubh + (size_t)r0 * 1024 + sc0, &Ul[0][d0]);
  gl_lds16(ubh + (size_t)r1 * 1024 + sc1, &Ul[0][d1]);
  __syncthreads();   // tile 0 landed
  int ub = 0, pub = 0;   // U buffer of tile st / tile st-1
  for (int st = 0; st < 16; ++st){
    int s0 = st * 64;
    int kb = st & 1;
    // ---- stage tile st+1 (K -> kb^1 [tenant st-1: QK done phase st-1]; U -> ub+1 [tenant st-2: PV done phase st-1])
    if (st < 15){
      int s1 = s0 + 64;
      int nub = (ub == 2) ? 0 : ub + 1;
      gl_lds16(qbh + (s1 + r0) * 64 + sc0, &Kl[kb ^ 1][d0]);
      gl_lds16(qbh + (s1 + r1) * 64 + sc1, &Kl[kb ^ 1][d1]);
      gl_lds16(ubh + (size_t)r0 * 1024 + s1 + sc0, &Ul[nub][d0]);
      gl_lds16(ubh + (size_t)r1 * 1024 + s1 + sc1, &Ul[nub][d1]);
    }
    // ---- PV(st-1): W from last phase, U from Ul[pub] — ready at phase start, independent chain
    if (st > 0){
      const u16* Up = &Ul[pub][0];
      __builtin_amdgcn_s_setprio(1);
      #pragma unroll
      for (int m_g = 0; m_g < 4; ++m_g){
        int base = (m_g >> 1) * 8 + (m_g & 1) * 4;
        i32x2 sw0 = __builtin_amdgcn_permlane32_swap((int)W[base + 0], (int)W[base + 2], false, false);
        i32x2 sw1 = __builtin_amdgcn_permlane32_swap((int)W[base + 1], (int)W[base + 3], false, false);
        union { u32 wd[4]; bf16x8 v; } pa;
        pa.wd[0] = (u32)sw0[0]; pa.wd[1] = (u32)sw1[0]; pa.wd[2] = (u32)sw0[1]; pa.wd[3] = (u32)sw1[1];
        bf16x8 u0 = *(const bf16x8*)&Up[swz(lo, m_g * 32 + hi * 16)];
        bf16x8 u1 = *(const bf16x8*)&Up[swz(32 + lo, m_g * 32 + hi * 16)];
        o0 = __builtin_amdgcn_mfma_f32_32x32x16_bf16(pa.v, u0, o0, 0, 0, 0);
        o1 = __builtin_amdgcn_mfma_f32_32x32x16_bf16(pa.v, u1, o1, 0, 0, 0);
      }
      __builtin_amdgcn_s_setprio(0);
    }
    // ---- QK(st): both ts halves, independent of PV above
    const u16* Kc = &Kl[kb][0];
    f32x16 sfA = zero16, sfB = zero16;
    __builtin_amdgcn_s_setprio(1);
    #pragma unroll
    for (int kd = 0; kd < 4; ++kd){
      bf16x8 kA = *(const bf16x8*)&Kc[swz(lo, kd * 32 + hi * 16)];
      sfA = __builtin_amdgcn_mfma_f32_32x32x16_bf16(kA, qB[kd], sfA, 0, 0, 0);
    }
    #pragma unroll
    for (int kd = 0; kd < 4; ++kd){
      bf16x8 kB = *(const bf16x8*)&Kc[swz(32 + lo, kd * 32 + hi * 16)];
      sfB = __builtin_amdgcn_mfma_f32_32x32x16_bf16(kB, qB[kd], sfB, 0, 0, 0);
    }
    __builtin_amdgcn_s_setprio(0);
    // ---- SM(st): p = 2^(S*C1 - qsq_s_scaled) -> W (consumed by PV next phase)
    {
      f32x4 qs_[4];
      #pragma unroll
      for (int q = 0; q < 4; ++q)
        qs_[q] = *(const f32x4*)(qsb + s0 + q * 8 + hi * 4);
      float p[16];
      #pragma unroll
      for (int r = 0; r < 16; ++r)
        p[r] = exp2_raw(fmaf(sfA[r], C1, -qs_[r >> 2][r & 3]));
      l_c += (((p[0] + p[1]) + (p[2] + p[3])) + ((p[4] + p[5]) + (p[6] + p[7])))
           + (((p[8] + p[9]) + (p[10] + p[11])) + ((p[12] + p[13]) + (p[14] + p[15])));
      #pragma unroll
      for (int q = 0; q < 8; ++q)
        W[q] = ((u32)f2bf_fast(p[2 * q + 1]) << 16) | (u32)f2bf_fast(p[2 * q]);
    }
    {
      f32x4 qs_[4];
      #pragma unroll
      for (int q = 0; q < 4; ++q)
        qs_[q] = *(const f32x4*)(qsb + s0 + 32 + q * 8 + hi * 4);
      float p[16];
      #pragma unroll
      for (int r = 0; r < 16; ++r)
        p[r] = exp2_raw(fmaf(sfB[r], C1, -qs_[r >> 2][r & 3]));
      l_c += (((p[0] + p[1]) + (p[2] + p[3])) + ((p[4] + p[5]) + (p[6] + p[7])))
           + (((p[8] + p[9]) + (p[10] + p[11])) + ((p[12] + p[13]) + (p[14] + p[15])));
      #pragma unroll
      for (int q = 0; q < 8; ++q)
        W[8 + q] = ((u32)f2bf_fast(p[2 * q + 1]) << 16) | (u32)f2bf_fast(p[2 * q]);
    }
    __syncthreads();   // drains vmcnt(0): tile st+1 landed; all reads of this phase done
    pub = ub;
    ub = (ub == 2) ? 0 : ub + 1;
  }
  // ---- epilogue: PV(15)
  {
    const u16* Up = &Ul[pub][0];
    #pragma unroll
    for (int m_g = 0; m_g < 4; ++m_g){
      int base = (m_g >> 1) * 8 + (m_g & 1) * 4;
      i32x2 sw0 = __builtin_amdgcn_permlane32_swap((int)W[base + 0], (int)W[base + 2], false, false);
      i32x2 sw1 = __builtin_amdgcn_permlane32_swap((int)W[base + 1], (int)W[base + 3], false, false);
      union { u32 wd[4]; bf16x8 v; } pa;
      pa.wd[0] = (u32)sw0[0]; pa.wd[1] = (u32)sw1[0]; pa.wd[2] = (u32)sw0[1]; pa.wd[3] = (u32)sw1[1];
      bf16x8 u0 = *(const bf16x8*)&Up[swz(lo, m_g * 32 + hi * 16)];
      bf16x8 u1 = *(const bf16x8*)&Up[swz(32 + lo, m_g * 32 + hi * 16)];
      o0 = __builtin_amdgcn_mfma_f32_32x32x16_bf16(pa.v, u0, o0, 0, 0, 0);
      o1 = __builtin_amdgcn_mfma_f32_32x32x16_bf16(pa.v, u1, o1, 0, 0, 0);
    }
  }
  // l: combine the two hi-halves; lane j then holds l for t = j&31
  l_c += __shfl_xor(l_c, 32);
  float inv = 1.0f / l_c;
  #pragma unroll
  for (int r = 0; r < 16; ++r){
    int tr = (r & 3) + 8 * (r >> 2) + 4 * hi;
    float invr = __shfl(inv, tr);
    size_t rowb = ((size_t)((t0 + tr) * 8 + b)) * 1024 + h * 64;
    obm[rowb + lo] = f2bf(o0[r] * invr);
    obm[rowb + 32 + lo] = f2bf(o1[r] * invr);
  }
}

extern "C" void kernel_launch(void* const* d_in, const int* in_sizes, int n_in,
                              void* d_out, int out_size, void* d_ws, size_t ws_size,
                              hipStream_t stream) {
  const float* x   = (const float*)d_in[0];
  const float* qw  = (const float*)d_in[1];
  const float* vw  = (const float*)d_in[2];
  const float* ow  = (const float*)d_in[3];
  const float* ob_bias = (const float*)d_in[4];
  float* out = (float*)d_out;

  // d_out (32 MiB) doubles as scratch:
  //  - Bp partials (2 MiB) live at d_out front, consumed by k_bred before gemm1 writes qb there
  //  - qb (16 MiB) + ubt (16 MiB) fill it afterwards; all dead before gemm2 writes `out`.
  float* Bp = (float*)d_out;
  u16* qb  = (u16*)d_out;                                     // [bh][t][d]  16 MiB
  u16* ubt = (u16*)((char*)d_out + (size_t)16 * 1024 * 1024); // [bh][d][t]  16 MiB

  char* ws = (char*)d_ws;
  size_t off = 0;
  auto alloc = [&](size_t bytes) -> void* {
    void* p = ws + off;
    off += (bytes + 255) & ~(size_t)255;
    return p;
  };
  u16*   wqt = (u16*)  alloc((size_t)1024 * 1024 * 2);   // Wq^T bf16 [n][m]   2 MiB
  u16*   obm = (u16*)  alloc((size_t)8192 * 1024 * 2);   // attn out bf16     16 MiB
  float* qsq = (float*)alloc((size_t)128 * 1024 * 4);    // scaled |q|^2     0.5 MiB
  u16*   Bt  = (u16*)  alloc((size_t)16 * 64 * 64 * 2);  // B_h^T bf16      0.125 MiB

  k_bmatp<<<128, 256, 0, stream>>>(qw, vw, Bp);
  k_bred<<<256, 256, 0, stream>>>(Bp, Bt);
  k_wqt<<<dim3(16, 16), 256, 0, stream>>>(qw, wqt);
  // GEMM1: q = x @ Wq  (A = x f32 cast-on-stage, B = Wq^T bf16) -> qb scatter
  k_gemm<1, 0, 0><<<512, 256, 0, stream>>>(x, wqt, qb, nullptr, 8192, 1024, 1024);
  k_u<<<2048, 64, 0, stream>>>(qb, Bt, ubt, qsq);
  k_attn<<<1024, 256, 0, stream>>>(qb, ubt, qsq, obm);
  // GEMM2: out = obm @ out_w^T + b  (A = obm bf16, B = out_w f32 cast-on-stage)
  k_gemm<0, 1, 1><<<512, 256, 0, stream>>>(obm, ow, out, ob_bias, 8192, 1024, 1024);
}

// Round 12
// 147.322 us; speedup vs baseline: 1.0294x; 1.0294x over previous
//
#include <hip/hip_runtime.h>
#include <hip/hip_bf16.h>

#define T_ 1024
#define N_ 8
#define D_ 1024
#define H_ 16
#define HD_ 64

typedef __attribute__((ext_vector_type(8))) short bf16x8;
typedef __attribute__((ext_vector_type(4))) float f32x4;
typedef __attribute__((ext_vector_type(16))) float f32x16;
typedef __attribute__((ext_vector_type(4))) int i32x4;
typedef __attribute__((ext_vector_type(2))) int i32x2;
typedef unsigned short u16;
typedef unsigned int u32;

__device__ __forceinline__ float bf2f(u16 u){
  union { float f; unsigned int i; } v; v.i = ((unsigned int)u) << 16; return v.f;
}
__device__ __forceinline__ u16 f2bf(float f){
  union { float f; unsigned int i; } v; v.f = f;
  unsigned int r = v.i + 0x7FFFu + ((v.i >> 16) & 1u);
  return (u16)(r >> 16);
}
__device__ __forceinline__ u16 f2bf_fast(float f){
  __hip_bfloat16 h = __float2bfloat16(f);   // RNE; compiler packs pairs into v_cvt_pk_bf16_f32
  return *reinterpret_cast<u16*>(&h);
}
// raw v_exp_f32: args are well inside normal range (p<=e^15), skip libm fixup tail
__device__ __forceinline__ float exp2_raw(float x){
  float r;
  asm("v_exp_f32 %0, %1" : "=v"(r) : "v"(x));
  return r;
}
// async global->LDS, 16B per lane, dest = wave-uniform base + lane*16
__device__ __forceinline__ void gl_lds16(const u16* g, u16* l){
  __builtin_amdgcn_global_load_lds(
      (const __attribute__((address_space(1))) unsigned int*)g,
      (__attribute__((address_space(3))) unsigned int*)(unsigned int)(unsigned long long)l,
      16, 0, 0);
}

// ---------------- transpose+cast Wq (D x D) -> Wqt[n][m] bf16 ----------------
__global__ __launch_bounds__(256) void k_wqt(const float* __restrict__ Wq, u16* __restrict__ Wqt){
  __shared__ float tld[64][65];
  int m0 = blockIdx.x * 64, n0 = blockIdx.y * 64;
  int col = threadIdx.x & 63, rq = threadIdx.x >> 6;
  #pragma unroll
  for (int p = 0; p < 16; ++p){
    int row = rq * 16 + p;
    tld[row][col] = Wq[(size_t)(m0 + row) * D_ + n0 + col];
  }
  __syncthreads();
  #pragma unroll
  for (int p = 0; p < 16; ++p){
    int row = rq * 16 + p;
    Wqt[(size_t)(n0 + row) * D_ + m0 + col] = f2bf(tld[col][row]);
  }
}

// ---------------- Bp[sp][h][d][e] partials of sum_m qw[m,h,e]*vw[m,h,d] (MFMA split-K) ----------------
__global__ __launch_bounds__(256) void k_bmatp(const float* __restrict__ qw, const float* __restrict__ vw,
                                               float* __restrict__ Bp){
  int h = (int)blockIdx.x >> 3, sp = (int)blockIdx.x & 7;
  int tid = threadIdx.x, lane = tid & 63, w = tid >> 6;
  int g = lane >> 4, c = lane & 15;
  __shared__ u16 Qt[64 * 72];  // [e][m] transposed, bf16
  __shared__ u16 Vt[64 * 72];  // [d][m]
  f32x4 zero = {0.f, 0.f, 0.f, 0.f};
  f32x4 acc[4];
  #pragma unroll
  for (int eb = 0; eb < 4; ++eb) acc[eb] = zero;
  int m = tid >> 2, cg = tid & 3;
  for (int mt = sp * 128; mt < sp * 128 + 128; mt += 64){
    __syncthreads();
    #pragma unroll
    for (int q = 0; q < 4; ++q){
      int e0 = cg * 16 + q * 4;
      f32x4 vq = *(const f32x4*)(qw + (size_t)(mt + m) * D_ + h * 64 + e0);
      f32x4 vv = *(const f32x4*)(vw + (size_t)(mt + m) * D_ + h * 64 + e0);
      #pragma unroll
      for (int j = 0; j < 4; ++j){
        Qt[(e0 + j) * 72 + m] = f2bf_fast(vq[j]);
        Vt[(e0 + j) * 72 + m] = f2bf_fast(vv[j]);
      }
    }
    __syncthreads();
    #pragma unroll
    for (int kk = 0; kk < 2; ++kk){
      bf16x8 av = *(const bf16x8*)&Vt[(w * 16 + c) * 72 + kk * 32 + g * 8];
      #pragma unroll
      for (int eb = 0; eb < 4; ++eb){
        bf16x8 bq = *(const bf16x8*)&Qt[(eb * 16 + c) * 72 + kk * 32 + g * 8];
        acc[eb] = __builtin_amdgcn_mfma_f32_16x16x32_bf16(av, bq, acc[eb], 0, 0, 0);
      }
    }
  }
  #pragma unroll
  for (int eb = 0; eb < 4; ++eb)
    #pragma unroll
    for (int r = 0; r < 4; ++r){
      int d = w * 16 + g * 4 + r, e = eb * 16 + c;
      Bp[(((size_t)sp * 16 + h) * 64 + d) * 64 + e] = acc[eb][r];
    }
}

// ---------------- reduce 8 partials -> Bt bf16 ----------------
__global__ __launch_bounds__(256) void k_bred(const float* __restrict__ Bp, u16* __restrict__ Bt){
  int i = blockIdx.x * 256 + threadIdx.x;   // 65536 total
  float s = 0.f;
  #pragma unroll
  for (int j = 0; j < 8; ++j) s += Bp[(size_t)j * 65536 + i];
  Bt[i] = f2bf(s * 0.125f);
}

// swizzled u16-index within a [rows][64] u16 LDS tile: XOR byte-bits 4-6 with row&7
__device__ __forceinline__ int swz(int row, int colbyte){
  return row * 64 + (((colbyte) ^ ((row & 7) << 4)) >> 1);
}

// ---------------- 128x128 bf16 MFMA GEMM, A[MxK] @ B^T (B given [N][K]) ----------------
template<int A_F32, int B_F32, int EPI>
__global__ __launch_bounds__(256) void k_gemm(const void* __restrict__ A_, const void* __restrict__ B_,
                                              void* __restrict__ Cv, const float* __restrict__ bias,
                                              int M, int N, int K){
  int nbn = N >> 7;
  int ii = (int)blockIdx.x;
  int sw = (ii & 7) * 64 + (ii >> 3);      // XCD-contiguous chunks (512 = 8*64 blocks)
  int bm = sw / nbn, bn = sw % nbn;
  int tid = threadIdx.x, lane = tid & 63, wid = tid >> 6;
  int wr = wid >> 1, wc = wid & 1, g = lane >> 4, c = lane & 15;
  __shared__ u16 As[128 * 64];
  __shared__ u16 Bs[128 * 64];
  f32x4 zero = {0.f, 0.f, 0.f, 0.f};
  f32x4 acc[4][4];
  #pragma unroll
  for (int m = 0; m < 4; ++m)
    #pragma unroll
    for (int n = 0; n < 4; ++n) acc[m][n] = zero;
  for (int kt = 0; kt < K; kt += 64){
    __syncthreads();
    #pragma unroll
    for (int p = 0; p < 4; ++p){
      int ci = tid + p * 256;
      int row = ci >> 3, c8 = ci & 7;
      int dst = swz(row, c8 * 16);
      if (A_F32){
        const float* A = (const float*)A_;
        const float* src = A + (size_t)(bm * 128 + row) * K + kt + c8 * 8;
        f32x4 v0 = *(const f32x4*)src;
        f32x4 v1 = *(const f32x4*)(src + 4);
        union { u16 u[8]; i32x4 v; } pk;
        #pragma unroll
        for (int j = 0; j < 4; ++j){ pk.u[j] = f2bf_fast(v0[j]); pk.u[4 + j] = f2bf_fast(v1[j]); }
        *(i32x4*)&As[dst] = pk.v;
      } else {
        const u16* A = (const u16*)A_;
        *(i32x4*)&As[dst] = *(const i32x4*)(A + (size_t)(bm * 128 + row) * K + kt + c8 * 8);
      }
      if (B_F32){
        const float* B = (const float*)B_;
        const float* src = B + (size_t)(bn * 128 + row) * K + kt + c8 * 8;
        f32x4 v0 = *(const f32x4*)src;
        f32x4 v1 = *(const f32x4*)(src + 4);
        union { u16 u[8]; i32x4 v; } pk;
        #pragma unroll
        for (int j = 0; j < 4; ++j){ pk.u[j] = f2bf_fast(v0[j]); pk.u[4 + j] = f2bf_fast(v1[j]); }
        *(i32x4*)&Bs[dst] = pk.v;
      } else {
        const u16* B = (const u16*)B_;
        *(i32x4*)&Bs[dst] = *(const i32x4*)(B + (size_t)(bn * 128 + row) * K + kt + c8 * 8);
      }
    }
    __syncthreads();
    #pragma unroll
    for (int kk = 0; kk < 2; ++kk){
      bf16x8 af[4], bfr[4];
      #pragma unroll
      for (int m = 0; m < 4; ++m){
        int row = wr * 64 + m * 16 + c;
        af[m] = *(const bf16x8*)&As[swz(row, kk * 64 + g * 16)];
      }
      #pragma unroll
      for (int n = 0; n < 4; ++n){
        int row = wc * 64 + n * 16 + c;
        bfr[n] = *(const bf16x8*)&Bs[swz(row, kk * 64 + g * 16)];
      }
      #pragma unroll
      for (int m = 0; m < 4; ++m)
        #pragma unroll
        for (int n = 0; n < 4; ++n)
          acc[m][n] = __builtin_amdgcn_mfma_f32_16x16x32_bf16(af[m], bfr[n], acc[m][n], 0, 0, 0);
    }
  }
  #pragma unroll
  for (int m = 0; m < 4; ++m)
    #pragma unroll
    for (int n = 0; n < 4; ++n)
      #pragma unroll
      for (int r = 0; r < 4; ++r){
        int row = bm * 128 + wr * 64 + m * 16 + g * 4 + r;
        int col = bn * 128 + wc * 64 + n * 16 + c;
        float v = acc[m][n][r];
        if (EPI == 0){
          int t = row >> 3, b = row & 7, hh = col >> 6, dd = col & 63;
          ((u16*)Cv)[(((size_t)(b * H_ + hh)) * T_ + t) * HD_ + dd] = f2bf(v);
        } else {
          ((float*)Cv)[(size_t)row * N + col] = v + bias[col];
        }
      }
}

// ---------------- u^T = B_h^T q^T per (bh, 64-t tile); also scaled q_sq. 1 wave. ----------------
__global__ __launch_bounds__(64) void k_u(const u16* __restrict__ qb, const u16* __restrict__ Bt,
                                          u16* __restrict__ ubt, float* __restrict__ qsq){
  int bh = blockIdx.x >> 4, tt = blockIdx.x & 15;
  int h = bh & 15, t0 = tt * 64;
  int lane = threadIdx.x, g = lane >> 4, c = lane & 15;
  const float QS_SCALE = 0.125f * 1.44269504088896340736f;
  bf16x8 af[4][2], bq[4][2];
  #pragma unroll
  for (int mf = 0; mf < 4; ++mf)
    #pragma unroll
    for (int kk = 0; kk < 2; ++kk)
      af[mf][kk] = *(const bf16x8*)(Bt + ((size_t)(h * 64 + mf * 16 + c)) * 64 + kk * 32 + g * 8);
  #pragma unroll
  for (int nf = 0; nf < 4; ++nf)
    #pragma unroll
    for (int kk = 0; kk < 2; ++kk)
      bq[nf][kk] = *(const bf16x8*)(qb + ((size_t)(bh * 1024 + t0 + nf * 16 + c)) * 64 + kk * 32 + g * 8);
  // q_sq from the same bf16 q; prescaled by 0.125*log2(e)
  #pragma unroll
  for (int nf = 0; nf < 4; ++nf){
    float ss = 0.f;
    #pragma unroll
    for (int kk = 0; kk < 2; ++kk)
      #pragma unroll
      for (int j = 0; j < 8; ++j){ float f = bf2f((u16)bq[nf][kk][j]); ss = fmaf(f, f, ss); }
    ss += __shfl_xor(ss, 16);
    ss += __shfl_xor(ss, 32);
    if (lane < 16) qsq[(size_t)bh * 1024 + t0 + nf * 16 + lane] = ss * QS_SCALE;
  }
  f32x4 zero = {0.f, 0.f, 0.f, 0.f};
  f32x4 acc[4][4];
  #pragma unroll
  for (int mf = 0; mf < 4; ++mf)
    #pragma unroll
    for (int nf = 0; nf < 4; ++nf) acc[mf][nf] = zero;
  #pragma unroll
  for (int kk = 0; kk < 2; ++kk)
    #pragma unroll
    for (int mf = 0; mf < 4; ++mf)
      #pragma unroll
      for (int nf = 0; nf < 4; ++nf)
        acc[mf][nf] = __builtin_amdgcn_mfma_f32_16x16x32_bf16(af[mf][kk], bq[nf][kk], acc[mf][nf], 0, 0, 0);
  #pragma unroll
  for (int mf = 0; mf < 4; ++mf)
    #pragma unroll
    for (int nf = 0; nf < 4; ++nf)
      #pragma unroll
      for (int r = 0; r < 4; ++r)
        ubt[((size_t)(bh * 64 + mf * 16 + g * 4 + r)) * 1024 + t0 + nf * 16 + c] = f2bf(acc[mf][nf][r]);
}

// ---------------- L2 attention: TBLK=128, pipelined PV one phase behind QK ----------------
// Phase st: PV(st-1) [reads U[(st-1)&1], W regs from last phase] -> barrier1 (cheap:
// no outstanding vmem) -> stage(st+1) [K->K[(st+1)&1], U->U[(st+1)&1]=U[(st-1)&1],
// safe after barrier1] -> QK(st) [K[st&1]] -> SM(st) [Qs LDS panel, no vmcnt] ->
// barrier2 (drains stage loads; they had QK+SM to land). K/U double-buffered;
// Qs staged once. LDS = 16+16+4 = 36 KB -> 4 blocks/CU, grid 1024 = 256x4, no tail.
__global__ __launch_bounds__(256, 4) void k_attn(const u16* __restrict__ qb, const u16* __restrict__ ubt,
                                                 const float* __restrict__ qsq, u16* __restrict__ obm){
  int i = (int)blockIdx.x;
  // XCD grouping: XCD (i&7) owns bh in [16*(i&7), ...+16), all 8 t-tiles.
  int bh = ((i & 7) << 4) + (i >> 6);
  int tt = (i >> 3) & 7;
  int b = bh >> 4, h = bh & 15;
  int tid = threadIdx.x, w = tid >> 6, lane = tid & 63;
  int lo = lane & 31, hi = lane >> 5;
  __shared__ u16 Kl[2][64 * 64];
  __shared__ u16 Ul[2][64 * 64];
  __shared__ float Qs[1024];
  const float C1 = 0.25f * 1.44269504088896340736f;
  int t0 = tt * 128 + w * 32;
  const u16* qbh = qb + (size_t)bh * 65536;    // [t][64]
  const u16* ubh = ubt + (size_t)bh * 65536;   // [e][1024]
  const float* qsb = qsq + (size_t)bh * 1024;
  // stage scaled-qsq panel once (4KB)
  *(f32x4*)&Qs[tid * 4] = *(const f32x4*)(qsb + tid * 4);
  // Q B-fragment (col=t=lo, k=d): 4 K=16 slices
  bf16x8 qB[4];
  #pragma unroll
  for (int kd = 0; kd < 4; ++kd)
    qB[kd] = *(const bf16x8*)(qbh + (t0 + lo) * 64 + kd * 16 + hi * 8);
  f32x16 o0 = {0,0,0,0,0,0,0,0,0,0,0,0,0,0,0,0};
  f32x16 o1 = {0,0,0,0,0,0,0,0,0,0,0,0,0,0,0,0};
  const f32x16 zero16 = {0,0,0,0,0,0,0,0,0,0,0,0,0,0,0,0};
  float l_c = 0.f;
  u32 W[16];
  // gload slots: per wave 2 calls per operand; slot=(w*2+j)*64+lane -> row=slot>>3, c8=slot&7
  int slot0 = (w * 2 + 0) * 64 + lane, slot1 = (w * 2 + 1) * 64 + lane;
  int r0 = slot0 >> 3, sc0 = ((slot0 & 7) ^ (r0 & 7)) * 8;   // pre-swizzled source chunk
  int r1 = slot1 >> 3, sc1 = ((slot1 & 7) ^ (r1 & 7)) * 8;
  int d0 = (w * 2 + 0) * 512, d1 = (w * 2 + 1) * 512;
  // prologue: stage tile 0 into K[0]/U[0]
  gl_lds16(qbh + r0 * 64 + sc0, &Kl[0][d0]);
  gl_lds16(qbh + r1 * 64 + sc1, &Kl[0][d1]);
  gl_lds16(ubh + (size_t)r0 * 1024 + sc0, &Ul[0][d0]);
  gl_lds16(ubh + (size_t)r1 * 1024 + sc1, &Ul[0][d1]);
  __syncthreads();   // tile 0 + Qs landed
  for (int st = 0; st < 16; ++st){
    int s0 = st * 64;
    // ---- PV(st-1): W from last phase, U from Ul[(st-1)&1] — independent MFMA chain
    if (st > 0){
      const u16* Up = &Ul[(st - 1) & 1][0];
      __builtin_amdgcn_s_setprio(1);
      #pragma unroll
      for (int m_g = 0; m_g < 4; ++m_g){
        int base = (m_g >> 1) * 8 + (m_g & 1) * 4;
        i32x2 sw0 = __builtin_amdgcn_permlane32_swap((int)W[base + 0], (int)W[base + 2], false, false);
        i32x2 sw1 = __builtin_amdgcn_permlane32_swap((int)W[base + 1], (int)W[base + 3], false, false);
        union { u32 wd[4]; bf16x8 v; } pa;
        pa.wd[0] = (u32)sw0[0]; pa.wd[1] = (u32)sw1[0]; pa.wd[2] = (u32)sw0[1]; pa.wd[3] = (u32)sw1[1];
        bf16x8 u0 = *(const bf16x8*)&Up[swz(lo, m_g * 32 + hi * 16)];
        bf16x8 u1 = *(const bf16x8*)&Up[swz(32 + lo, m_g * 32 + hi * 16)];
        o0 = __builtin_amdgcn_mfma_f32_32x32x16_bf16(pa.v, u0, o0, 0, 0, 0);
        o1 = __builtin_amdgcn_mfma_f32_32x32x16_bf16(pa.v, u1, o1, 0, 0, 0);
      }
      __builtin_amdgcn_s_setprio(0);
    }
    __syncthreads();   // cheap: all PV reads of U[(st-1)&1] done; no outstanding vmem
    // ---- stage tile st+1 (K -> K[(st+1)&1] [tenant st-1, QK done]; U -> U[(st+1)&1] [PV just finished])
    if (st < 15){
      int s1 = s0 + 64;
      int nb = (st + 1) & 1;
      gl_lds16(qbh + (s1 + r0) * 64 + sc0, &Kl[nb][d0]);
      gl_lds16(qbh + (s1 + r1) * 64 + sc1, &Kl[nb][d1]);
      gl_lds16(ubh + (size_t)r0 * 1024 + s1 + sc0, &Ul[nb][d0]);
      gl_lds16(ubh + (size_t)r1 * 1024 + s1 + sc1, &Ul[nb][d1]);
    }
    // ---- QK(st)
    const u16* Kc = &Kl[st & 1][0];
    f32x16 sfA = zero16, sfB = zero16;
    __builtin_amdgcn_s_setprio(1);
    #pragma unroll
    for (int kd = 0; kd < 4; ++kd){
      bf16x8 kA = *(const bf16x8*)&Kc[swz(lo, kd * 32 + hi * 16)];
      sfA = __builtin_amdgcn_mfma_f32_32x32x16_bf16(kA, qB[kd], sfA, 0, 0, 0);
    }
    #pragma unroll
    for (int kd = 0; kd < 4; ++kd){
      bf16x8 kB = *(const bf16x8*)&Kc[swz(32 + lo, kd * 32 + hi * 16)];
      sfB = __builtin_amdgcn_mfma_f32_32x32x16_bf16(kB, qB[kd], sfB, 0, 0, 0);
    }
    __builtin_amdgcn_s_setprio(0);
    // ---- SM(st): p = 2^(S*C1 - qsq_s_scaled) from Qs (LDS, no vmcnt) -> W
    {
      f32x4 qs_[4];
      #pragma unroll
      for (int q = 0; q < 4; ++q)
        qs_[q] = *(const f32x4*)&Qs[s0 + q * 8 + hi * 4];
      float p[16];
      #pragma unroll
      for (int r = 0; r < 16; ++r)
        p[r] = exp2_raw(fmaf(sfA[r], C1, -qs_[r >> 2][r & 3]));
      l_c += (((p[0] + p[1]) + (p[2] + p[3])) + ((p[4] + p[5]) + (p[6] + p[7])))
           + (((p[8] + p[9]) + (p[10] + p[11])) + ((p[12] + p[13]) + (p[14] + p[15])));
      #pragma unroll
      for (int q = 0; q < 8; ++q)
        W[q] = ((u32)f2bf_fast(p[2 * q + 1]) << 16) | (u32)f2bf_fast(p[2 * q]);
    }
    {
      f32x4 qs_[4];
      #pragma unroll
      for (int q = 0; q < 4; ++q)
        qs_[q] = *(const f32x4*)&Qs[s0 + 32 + q * 8 + hi * 4];
      float p[16];
      #pragma unroll
      for (int r = 0; r < 16; ++r)
        p[r] = exp2_raw(fmaf(sfB[r], C1, -qs_[r >> 2][r & 3]));
      l_c += (((p[0] + p[1]) + (p[2] + p[3])) + ((p[4] + p[5]) + (p[6] + p[7])))
           + (((p[8] + p[9]) + (p[10] + p[11])) + ((p[12] + p[13]) + (p[14] + p[15])));
      #pragma unroll
      for (int q = 0; q < 8; ++q)
        W[8 + q] = ((u32)f2bf_fast(p[2 * q + 1]) << 16) | (u32)f2bf_fast(p[2 * q]);
    }
    __syncthreads();   // drains vmcnt(0): tile st+1 landed (had QK+SM to cover)
  }
  // ---- epilogue: PV(15) reads Ul[1]
  {
    const u16* Up = &Ul[1][0];
    #pragma unroll
    for (int m_g = 0; m_g < 4; ++m_g){
      int base = (m_g >> 1) * 8 + (m_g & 1) * 4;
      i32x2 sw0 = __builtin_amdgcn_permlane32_swap((int)W[base + 0], (int)W[base + 2], false, false);
      i32x2 sw1 = __builtin_amdgcn_permlane32_swap((int)W[base + 1], (int)W[base + 3], false, false);
      union { u32 wd[4]; bf16x8 v; } pa;
      pa.wd[0] = (u32)sw0[0]; pa.wd[1] = (u32)sw1[0]; pa.wd[2] = (u32)sw0[1]; pa.wd[3] = (u32)sw1[1];
      bf16x8 u0 = *(const bf16x8*)&Up[swz(lo, m_g * 32 + hi * 16)];
      bf16x8 u1 = *(const bf16x8*)&Up[swz(32 + lo, m_g * 32 + hi * 16)];
      o0 = __builtin_amdgcn_mfma_f32_32x32x16_bf16(pa.v, u0, o0, 0, 0, 0);
      o1 = __builtin_amdgcn_mfma_f32_32x32x16_bf16(pa.v, u1, o1, 0, 0, 0);
    }
  }
  // l: combine the two hi-halves; lane j then holds l for t = j&31
  l_c += __shfl_xor(l_c, 32);
  float inv = 1.0f / l_c;
  #pragma unroll
  for (int r = 0; r < 16; ++r){
    int tr = (r & 3) + 8 * (r >> 2) + 4 * hi;
    float invr = __shfl(inv, tr);
    size_t rowb = ((size_t)((t0 + tr) * 8 + b)) * 1024 + h * 64;
    obm[rowb + lo] = f2bf(o0[r] * invr);
    obm[rowb + 32 + lo] = f2bf(o1[r] * invr);
  }
}

extern "C" void kernel_launch(void* const* d_in, const int* in_sizes, int n_in,
                              void* d_out, int out_size, void* d_ws, size_t ws_size,
                              hipStream_t stream) {
  const float* x   = (const float*)d_in[0];
  const float* qw  = (const float*)d_in[1];
  const float* vw  = (const float*)d_in[2];
  const float* ow  = (const float*)d_in[3];
  const float* ob_bias = (const float*)d_in[4];
  float* out = (float*)d_out;

  // d_out (32 MiB) doubles as scratch:
  //  - Bp partials (2 MiB) live at d_out front, consumed by k_bred before gemm1 writes qb there
  //  - qb (16 MiB) + ubt (16 MiB) fill it afterwards; all dead before gemm2 writes `out`.
  float* Bp = (float*)d_out;
  u16* qb  = (u16*)d_out;                                     // [bh][t][d]  16 MiB
  u16* ubt = (u16*)((char*)d_out + (size_t)16 * 1024 * 1024); // [bh][d][t]  16 MiB

  char* ws = (char*)d_ws;
  size_t off = 0;
  auto alloc = [&](size_t bytes) -> void* {
    void* p = ws + off;
    off += (bytes + 255) & ~(size_t)255;
    return p;
  };
  u16*   wqt = (u16*)  alloc((size_t)1024 * 1024 * 2);   // Wq^T bf16 [n][m]   2 MiB
  u16*   obm = (u16*)  alloc((size_t)8192 * 1024 * 2);   // attn out bf16     16 MiB
  float* qsq = (float*)alloc((size_t)128 * 1024 * 4);    // scaled |q|^2     0.5 MiB
  u16*   Bt  = (u16*)  alloc((size_t)16 * 64 * 64 * 2);  // B_h^T bf16      0.125 MiB

  k_bmatp<<<128, 256, 0, stream>>>(qw, vw, Bp);
  k_bred<<<256, 256, 0, stream>>>(Bp, Bt);
  k_wqt<<<dim3(16, 16), 256, 0, stream>>>(qw, wqt);
  // GEMM1: q = x @ Wq  (A = x f32 cast-on-stage, B = Wq^T bf16) -> qb scatter
  k_gemm<1, 0, 0><<<512, 256, 0, stream>>>(x, wqt, qb, nullptr, 8192, 1024, 1024);
  k_u<<<2048, 64, 0, stream>>>(qb, Bt, ubt, qsq);
  k_attn<<<1024, 256, 0, stream>>>(qb, ubt, qsq, obm);
  // GEMM2: out = obm @ out_w^T + b  (A = obm bf16, B = out_w f32 cast-on-stage)
  k_gemm<0, 1, 1><<<512, 256, 0, stream>>>(obm, ow, out, ob_bias, 8192, 1024, 1024);
}

// Round 13
// 140.776 us; speedup vs baseline: 1.0773x; 1.0465x over previous
//
#include <hip/hip_runtime.h>
#include <hip/hip_bf16.h>

#define T_ 1024
#define N_ 8
#define D_ 1024
#define H_ 16
#define HD_ 64

typedef __attribute__((ext_vector_type(8))) short bf16x8;
typedef __attribute__((ext_vector_type(4))) float f32x4;
typedef __attribute__((ext_vector_type(16))) float f32x16;
typedef __attribute__((ext_vector_type(4))) int i32x4;
typedef __attribute__((ext_vector_type(2))) int i32x2;
typedef __attribute__((ext_vector_type(4))) unsigned short u16x4;
typedef unsigned short u16;
typedef unsigned int u32;

__device__ __forceinline__ float bf2f(u16 u){
  union { float f; unsigned int i; } v; v.i = ((unsigned int)u) << 16; return v.f;
}
__device__ __forceinline__ u16 f2bf(float f){
  union { float f; unsigned int i; } v; v.f = f;
  unsigned int r = v.i + 0x7FFFu + ((v.i >> 16) & 1u);
  return (u16)(r >> 16);
}
__device__ __forceinline__ u16 f2bf_fast(float f){
  __hip_bfloat16 h = __float2bfloat16(f);   // RNE; compiler packs pairs into v_cvt_pk_bf16_f32
  return *reinterpret_cast<u16*>(&h);
}
// raw v_exp_f32: args are well inside normal range (p<=e^15), skip libm fixup tail
__device__ __forceinline__ float exp2_raw(float x){
  float r;
  asm("v_exp_f32 %0, %1" : "=v"(r) : "v"(x));
  return r;
}
// async global->LDS, 16B per lane, dest = wave-uniform base + lane*16
__device__ __forceinline__ void gl_lds16(const u16* g, u16* l){
  __builtin_amdgcn_global_load_lds(
      (const __attribute__((address_space(1))) unsigned int*)g,
      (__attribute__((address_space(3))) unsigned int*)(unsigned int)(unsigned long long)l,
      16, 0, 0);
}

// ---------------- cast f32 -> bf16, 4 elems/thread ----------------
__global__ __launch_bounds__(256) void k_cast(const float* __restrict__ in, u16* __restrict__ out){
  int i = (blockIdx.x * 256 + threadIdx.x) * 4;
  f32x4 v = *(const f32x4*)(in + i);
  u16x4 o;
  o[0] = f2bf(v[0]); o[1] = f2bf(v[1]); o[2] = f2bf(v[2]); o[3] = f2bf(v[3]);
  *(u16x4*)(out + i) = o;
}

// ---------------- transpose+cast Wq (D x D) -> Wqt[n][m] bf16 ----------------
__global__ __launch_bounds__(256) void k_wqt(const float* __restrict__ Wq, u16* __restrict__ Wqt){
  __shared__ float tld[64][65];
  int m0 = blockIdx.x * 64, n0 = blockIdx.y * 64;
  int col = threadIdx.x & 63, rq = threadIdx.x >> 6;
  #pragma unroll
  for (int p = 0; p < 16; ++p){
    int row = rq * 16 + p;
    tld[row][col] = Wq[(size_t)(m0 + row) * D_ + n0 + col];
  }
  __syncthreads();
  #pragma unroll
  for (int p = 0; p < 16; ++p){
    int row = rq * 16 + p;
    Wqt[(size_t)(n0 + row) * D_ + m0 + col] = f2bf(tld[col][row]);
  }
}

// ---------------- Bp[sp][h][d][e] partials of sum_m qw[m,h,e]*vw[m,h,d] (MFMA split-K) ----------------
__global__ __launch_bounds__(256) void k_bmatp(const float* __restrict__ qw, const float* __restrict__ vw,
                                               float* __restrict__ Bp){
  int h = (int)blockIdx.x >> 3, sp = (int)blockIdx.x & 7;
  int tid = threadIdx.x, lane = tid & 63, w = tid >> 6;
  int g = lane >> 4, c = lane & 15;
  __shared__ u16 Qt[64 * 72];  // [e][m] transposed, bf16
  __shared__ u16 Vt[64 * 72];  // [d][m]
  f32x4 zero = {0.f, 0.f, 0.f, 0.f};
  f32x4 acc[4];
  #pragma unroll
  for (int eb = 0; eb < 4; ++eb) acc[eb] = zero;
  int m = tid >> 2, cg = tid & 3;
  for (int mt = sp * 128; mt < sp * 128 + 128; mt += 64){
    __syncthreads();
    #pragma unroll
    for (int q = 0; q < 4; ++q){
      int e0 = cg * 16 + q * 4;
      f32x4 vq = *(const f32x4*)(qw + (size_t)(mt + m) * D_ + h * 64 + e0);
      f32x4 vv = *(const f32x4*)(vw + (size_t)(mt + m) * D_ + h * 64 + e0);
      #pragma unroll
      for (int j = 0; j < 4; ++j){
        Qt[(e0 + j) * 72 + m] = f2bf_fast(vq[j]);
        Vt[(e0 + j) * 72 + m] = f2bf_fast(vv[j]);
      }
    }
    __syncthreads();
    #pragma unroll
    for (int kk = 0; kk < 2; ++kk){
      bf16x8 av = *(const bf16x8*)&Vt[(w * 16 + c) * 72 + kk * 32 + g * 8];
      #pragma unroll
      for (int eb = 0; eb < 4; ++eb){
        bf16x8 bq = *(const bf16x8*)&Qt[(eb * 16 + c) * 72 + kk * 32 + g * 8];
        acc[eb] = __builtin_amdgcn_mfma_f32_16x16x32_bf16(av, bq, acc[eb], 0, 0, 0);
      }
    }
  }
  #pragma unroll
  for (int eb = 0; eb < 4; ++eb)
    #pragma unroll
    for (int r = 0; r < 4; ++r){
      int d = w * 16 + g * 4 + r, e = eb * 16 + c;
      Bp[(((size_t)sp * 16 + h) * 64 + d) * 64 + e] = acc[eb][r];
    }
}

// ---------------- reduce 8 partials -> Bt bf16 ----------------
__global__ __launch_bounds__(256) void k_bred(const float* __restrict__ Bp, u16* __restrict__ Bt){
  int i = blockIdx.x * 256 + threadIdx.x;   // 65536 total
  float s = 0.f;
  #pragma unroll
  for (int j = 0; j < 8; ++j) s += Bp[(size_t)j * 65536 + i];
  Bt[i] = f2bf(s * 0.125f);
}

// swizzled u16-index within a [rows][64] u16 LDS tile: XOR byte-bits 4-6 with row&7
__device__ __forceinline__ int swz(int row, int colbyte){
  return row * 64 + (((colbyte) ^ ((row & 7) << 4)) >> 1);
}

// ---------------- 128x128 bf16 MFMA GEMM, A[MxK] bf16 @ B^T ----------------
// A staged via global_load_lds (linear dest, pre-swizzled source). B: bf16 -> also
// gl_lds; f32 -> reg-load + cast + swizzled ds_write. m97 single-buffer 2-barrier loop.
// EPI=0: scatter to qb[bh][t][d] bf16 ;  EPI=1: C f32 + bias
template<int B_F32, int EPI>
__global__ __launch_bounds__(256) void k_gemm(const u16* __restrict__ A, const void* __restrict__ B_,
                                              void* __restrict__ Cv, const float* __restrict__ bias,
                                              int M, int N, int K){
  int nbn = N >> 7;
  int ii = (int)blockIdx.x;
  int sw = (ii & 7) * 64 + (ii >> 3);      // XCD-contiguous chunks (512 = 8*64 blocks)
  int bm = sw / nbn, bn = sw % nbn;
  int tid = threadIdx.x, lane = tid & 63, wid = tid >> 6;
  int wr = wid >> 1, wc = wid & 1, g = lane >> 4, c = lane & 15;
  __shared__ u16 As[128 * 64];
  __shared__ u16 Bs[128 * 64];
  // gl_lds slots: slot=(w*4+p)*64+lane, p=0..3; row=slot>>3, chunk c8=slot&7.
  // Linear dest = slot*8 u16; source chunk pre-swizzled: c8 ^ (row&7).
  int srowA[4], scolA[4], sdst[4];
  #pragma unroll
  for (int p = 0; p < 4; ++p){
    int slot = (wid * 4 + p) * 64 + lane;
    int row = slot >> 3, c8 = slot & 7;
    srowA[p] = row;
    scolA[p] = (c8 ^ (row & 7)) * 8;
    sdst[p] = slot * 8;
  }
  f32x4 zero = {0.f, 0.f, 0.f, 0.f};
  f32x4 acc[4][4];
  #pragma unroll
  for (int m = 0; m < 4; ++m)
    #pragma unroll
    for (int n = 0; n < 4; ++n) acc[m][n] = zero;
  for (int kt = 0; kt < K; kt += 64){
    __syncthreads();    // prev compute done reading LDS
    #pragma unroll
    for (int p = 0; p < 4; ++p)
      gl_lds16(A + (size_t)(bm * 128 + srowA[p]) * K + kt + scolA[p], &As[sdst[p]]);
    if (B_F32){
      const float* B = (const float*)B_;
      #pragma unroll
      for (int p = 0; p < 4; ++p){
        int ci = tid + p * 256;
        int row = ci >> 3, c8 = ci & 7;
        const float* src = B + (size_t)(bn * 128 + row) * K + kt + c8 * 8;
        f32x4 v0 = *(const f32x4*)src;
        f32x4 v1 = *(const f32x4*)(src + 4);
        union { u16 u[8]; i32x4 v; } pk;
        #pragma unroll
        for (int j = 0; j < 4; ++j){ pk.u[j] = f2bf_fast(v0[j]); pk.u[4 + j] = f2bf_fast(v1[j]); }
        *(i32x4*)&Bs[swz(row, c8 * 16)] = pk.v;
      }
    } else {
      const u16* B = (const u16*)B_;
      #pragma unroll
      for (int p = 0; p < 4; ++p)
        gl_lds16(B + (size_t)(bn * 128 + srowA[p]) * K + kt + scolA[p], &Bs[sdst[p]]);
    }
    __syncthreads();    // drains vmcnt/lgkm -> LDS ready (m97 pattern)
    #pragma unroll
    for (int kk = 0; kk < 2; ++kk){
      bf16x8 af[4], bfr[4];
      #pragma unroll
      for (int m = 0; m < 4; ++m){
        int row = wr * 64 + m * 16 + c;
        af[m] = *(const bf16x8*)&As[swz(row, kk * 64 + g * 16)];
      }
      #pragma unroll
      for (int n = 0; n < 4; ++n){
        int row = wc * 64 + n * 16 + c;
        bfr[n] = *(const bf16x8*)&Bs[swz(row, kk * 64 + g * 16)];
      }
      #pragma unroll
      for (int m = 0; m < 4; ++m)
        #pragma unroll
        for (int n = 0; n < 4; ++n)
          acc[m][n] = __builtin_amdgcn_mfma_f32_16x16x32_bf16(af[m], bfr[n], acc[m][n], 0, 0, 0);
    }
  }
  #pragma unroll
  for (int m = 0; m < 4; ++m)
    #pragma unroll
    for (int n = 0; n < 4; ++n)
      #pragma unroll
      for (int r = 0; r < 4; ++r){
        int row = bm * 128 + wr * 64 + m * 16 + g * 4 + r;
        int col = bn * 128 + wc * 64 + n * 16 + c;
        float v = acc[m][n][r];
        if (EPI == 0){
          int t = row >> 3, b = row & 7, hh = col >> 6, dd = col & 63;
          ((u16*)Cv)[(((size_t)(b * H_ + hh)) * T_ + t) * HD_ + dd] = f2bf(v);
        } else {
          ((float*)Cv)[(size_t)row * N + col] = v + bias[col];
        }
      }
}

// ---------------- u^T = B_h^T q^T per (bh, 64-t tile); also scaled q_sq. 1 wave. ----------------
__global__ __launch_bounds__(64) void k_u(const u16* __restrict__ qb, const u16* __restrict__ Bt,
                                          u16* __restrict__ ubt, float* __restrict__ qsq){
  int bh = blockIdx.x >> 4, tt = blockIdx.x & 15;
  int h = bh & 15, t0 = tt * 64;
  int lane = threadIdx.x, g = lane >> 4, c = lane & 15;
  const float QS_SCALE = 0.125f * 1.44269504088896340736f;
  bf16x8 af[4][2], bq[4][2];
  #pragma unroll
  for (int mf = 0; mf < 4; ++mf)
    #pragma unroll
    for (int kk = 0; kk < 2; ++kk)
      af[mf][kk] = *(const bf16x8*)(Bt + ((size_t)(h * 64 + mf * 16 + c)) * 64 + kk * 32 + g * 8);
  #pragma unroll
  for (int nf = 0; nf < 4; ++nf)
    #pragma unroll
    for (int kk = 0; kk < 2; ++kk)
      bq[nf][kk] = *(const bf16x8*)(qb + ((size_t)(bh * 1024 + t0 + nf * 16 + c)) * 64 + kk * 32 + g * 8);
  // q_sq from the same bf16 q; prescaled by 0.125*log2(e)
  #pragma unroll
  for (int nf = 0; nf < 4; ++nf){
    float ss = 0.f;
    #pragma unroll
    for (int kk = 0; kk < 2; ++kk)
      #pragma unroll
      for (int j = 0; j < 8; ++j){ float f = bf2f((u16)bq[nf][kk][j]); ss = fmaf(f, f, ss); }
    ss += __shfl_xor(ss, 16);
    ss += __shfl_xor(ss, 32);
    if (lane < 16) qsq[(size_t)bh * 1024 + t0 + nf * 16 + lane] = ss * QS_SCALE;
  }
  f32x4 zero = {0.f, 0.f, 0.f, 0.f};
  f32x4 acc[4][4];
  #pragma unroll
  for (int mf = 0; mf < 4; ++mf)
    #pragma unroll
    for (int nf = 0; nf < 4; ++nf) acc[mf][nf] = zero;
  #pragma unroll
  for (int kk = 0; kk < 2; ++kk)
    #pragma unroll
    for (int mf = 0; mf < 4; ++mf)
      #pragma unroll
      for (int nf = 0; nf < 4; ++nf)
        acc[mf][nf] = __builtin_amdgcn_mfma_f32_16x16x32_bf16(af[mf][kk], bq[nf][kk], acc[mf][nf], 0, 0, 0);
  #pragma unroll
  for (int mf = 0; mf < 4; ++mf)
    #pragma unroll
    for (int nf = 0; nf < 4; ++nf)
      #pragma unroll
      for (int r = 0; r < 4; ++r)
        ubt[((size_t)(bh * 64 + mf * 16 + g * 4 + r)) * 1024 + t0 + nf * 16 + c] = f2bf(acc[mf][nf][r]);
}

// ---------------- L2 attention: TBLK=128, dbuf gl_lds staging, m97 single-drain schedule ----------------
// (round-10 version, 54.4 us proven) prologue: issue gl_lds(buf0). Loop: __syncthreads
// (drains vmcnt -> cur buf ready; all waves done reading buf^1) -> issue gl_lds(buf^1, st+1)
// -> compute(buf). Loads overlap the full compute phase. qsq panel staged once.
__global__ __launch_bounds__(256, 4) void k_attn(const u16* __restrict__ qb, const u16* __restrict__ ubt,
                                                 const float* __restrict__ qsq, u16* __restrict__ obm){
  int i = (int)blockIdx.x;
  // XCD grouping: XCD (i&7) owns bh in [16*(i&7), ...+16), all 8 t-tiles.
  int bh = ((i & 7) << 4) + (i >> 6);
  int tt = (i >> 3) & 7;
  int b = bh >> 4, h = bh & 15;
  int tid = threadIdx.x, w = tid >> 6, lane = tid & 63;
  int lo = lane & 31, hi = lane >> 5;
  __shared__ u16 Kl[2][64 * 64];
  __shared__ u16 Ul[2][64 * 64];
  __shared__ float Qs[1024];
  const float C1 = 0.25f * 1.44269504088896340736f;
  int t0 = tt * 128 + w * 32;
  const u16* qbh = qb + (size_t)bh * 65536;    // [t][64]
  const u16* ubh = ubt + (size_t)bh * 65536;   // [e][1024]
  const float* qsb = qsq + (size_t)bh * 1024;
  // stage the whole scaled-qsq panel once (4KB)
  *(f32x4*)&Qs[tid * 4] = *(const f32x4*)(qsb + tid * 4);
  // Q B-fragment (col=t=lo, k=d): 4 K=16 slices
  bf16x8 qB[4];
  #pragma unroll
  for (int kd = 0; kd < 4; ++kd)
    qB[kd] = *(const bf16x8*)(qbh + (t0 + lo) * 64 + kd * 16 + hi * 8);
  f32x16 o0 = {0,0,0,0,0,0,0,0,0,0,0,0,0,0,0,0};
  f32x16 o1 = {0,0,0,0,0,0,0,0,0,0,0,0,0,0,0,0};
  const f32x16 zero16 = {0,0,0,0,0,0,0,0,0,0,0,0,0,0,0,0};
  float l_c = 0.f;
  // gload slots: per wave 2 calls per operand; slot=(w*2+j)*64+lane -> row=slot>>3, c8=slot&7
  int slot0 = (w * 2 + 0) * 64 + lane, slot1 = (w * 2 + 1) * 64 + lane;
  int r0 = slot0 >> 3, sc0 = ((slot0 & 7) ^ (r0 & 7)) * 8;   // pre-swizzled source chunk
  int r1 = slot1 >> 3, sc1 = ((slot1 & 7) ^ (r1 & 7)) * 8;
  int d0 = (w * 2 + 0) * 512, d1 = (w * 2 + 1) * 512;
  // prologue: issue tile-0 loads into buf 0
  gl_lds16(qbh + r0 * 64 + sc0, &Kl[0][d0]);
  gl_lds16(qbh + r1 * 64 + sc1, &Kl[0][d1]);
  gl_lds16(ubh + (size_t)r0 * 1024 + sc0, &Ul[0][d0]);
  gl_lds16(ubh + (size_t)r1 * 1024 + sc1, &Ul[0][d1]);
  int cur = 0;
  for (int st = 0; st < 16; ++st){
    int s0 = st * 64;
    __syncthreads();   // drains vmcnt(0): buf[cur] landed (full round in flight); all waves past buf[cur^1] reads
    if (st < 15){
      int s1 = s0 + 64;
      int nb = cur ^ 1;
      gl_lds16(qbh + (s1 + r0) * 64 + sc0, &Kl[nb][d0]);
      gl_lds16(qbh + (s1 + r1) * 64 + sc1, &Kl[nb][d1]);
      gl_lds16(ubh + (size_t)r0 * 1024 + s1 + sc0, &Ul[nb][d0]);
      gl_lds16(ubh + (size_t)r1 * 1024 + s1 + sc1, &Ul[nb][d1]);
    }
    const u16* Kc = &Kl[cur][0];
    const u16* Uc = &Ul[cur][0];
    #pragma unroll
    for (int ts = 0; ts < 2; ++ts){
      f32x16 sf = zero16;
      __builtin_amdgcn_s_setprio(1);
      #pragma unroll
      for (int kd = 0; kd < 4; ++kd){
        bf16x8 kA = *(const bf16x8*)&Kc[swz(ts * 32 + lo, kd * 32 + hi * 16)];
        sf = __builtin_amdgcn_mfma_f32_32x32x16_bf16(kA, qB[kd], sf, 0, 0, 0);
      }
      __builtin_amdgcn_s_setprio(0);
      f32x4 qs_[4];
      #pragma unroll
      for (int q = 0; q < 4; ++q)
        qs_[q] = *(const f32x4*)&Qs[s0 + ts * 32 + q * 8 + hi * 4];
      float p[16];
      #pragma unroll
      for (int r = 0; r < 16; ++r)
        p[r] = exp2_raw(fmaf(sf[r], C1, -qs_[r >> 2][r & 3]));
      float sA = ((p[0] + p[1]) + (p[2] + p[3])) + ((p[4] + p[5]) + (p[6] + p[7]));
      float sB = ((p[8] + p[9]) + (p[10] + p[11])) + ((p[12] + p[13]) + (p[14] + p[15]));
      l_c += sA + sB;
      u32 W[8];
      #pragma unroll
      for (int q = 0; q < 8; ++q)
        W[q] = ((u32)f2bf_fast(p[2 * q + 1]) << 16) | (u32)f2bf_fast(p[2 * q]);
      // PV for this ts: k-slices m_g = ts*2 + {0,1}
      #pragma unroll
      for (int ml = 0; ml < 2; ++ml){
        int m_g = ts * 2 + ml;
        int base = ml * 4;
        i32x2 sw0 = __builtin_amdgcn_permlane32_swap((int)W[base + 0], (int)W[base + 2], false, false);
        i32x2 sw1 = __builtin_amdgcn_permlane32_swap((int)W[base + 1], (int)W[base + 3], false, false);
        union { u32 wd[4]; bf16x8 v; } pa;
        pa.wd[0] = (u32)sw0[0]; pa.wd[1] = (u32)sw1[0]; pa.wd[2] = (u32)sw0[1]; pa.wd[3] = (u32)sw1[1];
        bf16x8 u0 = *(const bf16x8*)&Uc[swz(lo, m_g * 32 + hi * 16)];
        bf16x8 u1 = *(const bf16x8*)&Uc[swz(32 + lo, m_g * 32 + hi * 16)];
        __builtin_amdgcn_s_setprio(1);
        o0 = __builtin_amdgcn_mfma_f32_32x32x16_bf16(pa.v, u0, o0, 0, 0, 0);
        o1 = __builtin_amdgcn_mfma_f32_32x32x16_bf16(pa.v, u1, o1, 0, 0, 0);
        __builtin_amdgcn_s_setprio(0);
      }
    }
    cur ^= 1;
  }
  // l: combine the two hi-halves; lane j then holds l for t = j&31
  l_c += __shfl_xor(l_c, 32);
  float inv = 1.0f / l_c;
  #pragma unroll
  for (int r = 0; r < 16; ++r){
    int tr = (r & 3) + 8 * (r >> 2) + 4 * hi;
    float invr = __shfl(inv, tr);
    size_t rowb = ((size_t)((t0 + tr) * 8 + b)) * 1024 + h * 64;
    obm[rowb + lo] = f2bf(o0[r] * invr);
    obm[rowb + 32 + lo] = f2bf(o1[r] * invr);
  }
}

extern "C" void kernel_launch(void* const* d_in, const int* in_sizes, int n_in,
                              void* d_out, int out_size, void* d_ws, size_t ws_size,
                              hipStream_t stream) {
  const float* x   = (const float*)d_in[0];
  const float* qw  = (const float*)d_in[1];
  const float* vw  = (const float*)d_in[2];
  const float* ow  = (const float*)d_in[3];
  const float* ob_bias = (const float*)d_in[4];
  float* out = (float*)d_out;

  // d_out (32 MiB) doubles as scratch. Timeline:
  //  - xb (x cast to bf16) lives at d_out[16:32MB] until GEMM1 finishes.
  //  - Bp partials (2 MiB) at d_out[0:2MB], consumed by k_bred before GEMM1 writes qb there.
  //  - qb = d_out[0:16MB] (GEMM1 out); ubt = d_out[16:32MB] (k_u out, overwrites dead xb).
  //  - GEMM2 overwrites everything with the final result.
  float* Bp = (float*)d_out;
  u16* qb  = (u16*)d_out;                                     // [bh][t][d]  16 MiB
  u16* ubt = (u16*)((char*)d_out + (size_t)16 * 1024 * 1024); // [bh][d][t]  16 MiB
  u16* xb  = ubt;                                             // x bf16 (dead after GEMM1)

  char* ws = (char*)d_ws;
  size_t off = 0;
  auto alloc = [&](size_t bytes) -> void* {
    void* p = ws + off;
    off += (bytes + 255) & ~(size_t)255;
    return p;
  };
  u16*   wqt = (u16*)  alloc((size_t)1024 * 1024 * 2);   // Wq^T bf16 [n][m]   2 MiB
  u16*   obm = (u16*)  alloc((size_t)8192 * 1024 * 2);   // attn out bf16     16 MiB
  float* qsq = (float*)alloc((size_t)128 * 1024 * 4);    // scaled |q|^2     0.5 MiB
  u16*   Bt  = (u16*)  alloc((size_t)16 * 64 * 64 * 2);  // B_h^T bf16      0.125 MiB

  k_cast<<<8192, 256, 0, stream>>>(x, xb);
  k_bmatp<<<128, 256, 0, stream>>>(qw, vw, Bp);
  k_bred<<<256, 256, 0, stream>>>(Bp, Bt);
  k_wqt<<<dim3(16, 16), 256, 0, stream>>>(qw, wqt);
  // GEMM1: q = xb @ Wq (both bf16, gl_lds staging) -> qb scatter
  k_gemm<0, 0><<<512, 256, 0, stream>>>(xb, wqt, qb, nullptr, 8192, 1024, 1024);
  k_u<<<2048, 64, 0, stream>>>(qb, Bt, ubt, qsq);
  k_attn<<<1024, 256, 0, stream>>>(qb, ubt, qsq, obm);
  // GEMM2: out = obm @ out_w^T + b  (A = obm bf16 gl_lds, B = out_w f32 cast-on-stage)
  k_gemm<1, 1><<<512, 256, 0, stream>>>(obm, ow, out, ob_bias, 8192, 1024, 1024);
}

// Round 14
// 135.669 us; speedup vs baseline: 1.1178x; 1.0376x over previous
//
#include <hip/hip_runtime.h>
#include <hip/hip_bf16.h>

#define T_ 1024
#define N_ 8
#define D_ 1024
#define H_ 16
#define HD_ 64

typedef __attribute__((ext_vector_type(8))) short bf16x8;
typedef __attribute__((ext_vector_type(4))) float f32x4;
typedef __attribute__((ext_vector_type(16))) float f32x16;
typedef __attribute__((ext_vector_type(4))) int i32x4;
typedef __attribute__((ext_vector_type(2))) int i32x2;
typedef unsigned short u16;
typedef unsigned int u32;

__device__ __forceinline__ float bf2f(u16 u){
  union { float f; unsigned int i; } v; v.i = ((unsigned int)u) << 16; return v.f;
}
__device__ __forceinline__ u16 f2bf(float f){
  union { float f; unsigned int i; } v; v.f = f;
  unsigned int r = v.i + 0x7FFFu + ((v.i >> 16) & 1u);
  return (u16)(r >> 16);
}
__device__ __forceinline__ u16 f2bf_fast(float f){
  __hip_bfloat16 h = __float2bfloat16(f);   // RNE; compiler packs pairs into v_cvt_pk_bf16_f32
  return *reinterpret_cast<u16*>(&h);
}
// raw v_exp_f32: args are well inside normal range (p<=e^15), skip libm fixup tail
__device__ __forceinline__ float exp2_raw(float x){
  float r;
  asm("v_exp_f32 %0, %1" : "=v"(r) : "v"(x));
  return r;
}
// async global->LDS, 16B per lane, dest = wave-uniform base + lane*16
__device__ __forceinline__ void gl_lds16(const u16* g, u16* l){
  __builtin_amdgcn_global_load_lds(
      (const __attribute__((address_space(1))) unsigned int*)g,
      (__attribute__((address_space(3))) unsigned int*)(unsigned int)(unsigned long long)l,
      16, 0, 0);
}

// ---------------- transpose+cast Wq (D x D) -> Wqt[n][m] bf16 ----------------
__global__ __launch_bounds__(256) void k_wqt(const float* __restrict__ Wq, u16* __restrict__ Wqt){
  __shared__ float tld[64][65];
  int m0 = blockIdx.x * 64, n0 = blockIdx.y * 64;
  int col = threadIdx.x & 63, rq = threadIdx.x >> 6;
  #pragma unroll
  for (int p = 0; p < 16; ++p){
    int row = rq * 16 + p;
    tld[row][col] = Wq[(size_t)(m0 + row) * D_ + n0 + col];
  }
  __syncthreads();
  #pragma unroll
  for (int p = 0; p < 16; ++p){
    int row = rq * 16 + p;
    Wqt[(size_t)(n0 + row) * D_ + m0 + col] = f2bf(tld[col][row]);
  }
}

// ---------------- Bp[sp][h][d][e] partials of sum_m qw[m,h,e]*vw[m,h,d] (MFMA split-K) ----------------
__global__ __launch_bounds__(256) void k_bmatp(const float* __restrict__ qw, const float* __restrict__ vw,
                                               float* __restrict__ Bp){
  int h = (int)blockIdx.x >> 3, sp = (int)blockIdx.x & 7;
  int tid = threadIdx.x, lane = tid & 63, w = tid >> 6;
  int g = lane >> 4, c = lane & 15;
  __shared__ u16 Qt[64 * 72];  // [e][m] transposed, bf16
  __shared__ u16 Vt[64 * 72];  // [d][m]
  f32x4 zero = {0.f, 0.f, 0.f, 0.f};
  f32x4 acc[4];
  #pragma unroll
  for (int eb = 0; eb < 4; ++eb) acc[eb] = zero;
  int m = tid >> 2, cg = tid & 3;
  for (int mt = sp * 128; mt < sp * 128 + 128; mt += 64){
    __syncthreads();
    #pragma unroll
    for (int q = 0; q < 4; ++q){
      int e0 = cg * 16 + q * 4;
      f32x4 vq = *(const f32x4*)(qw + (size_t)(mt + m) * D_ + h * 64 + e0);
      f32x4 vv = *(const f32x4*)(vw + (size_t)(mt + m) * D_ + h * 64 + e0);
      #pragma unroll
      for (int j = 0; j < 4; ++j){
        Qt[(e0 + j) * 72 + m] = f2bf_fast(vq[j]);
        Vt[(e0 + j) * 72 + m] = f2bf_fast(vv[j]);
      }
    }
    __syncthreads();
    #pragma unroll
    for (int kk = 0; kk < 2; ++kk){
      bf16x8 av = *(const bf16x8*)&Vt[(w * 16 + c) * 72 + kk * 32 + g * 8];
      #pragma unroll
      for (int eb = 0; eb < 4; ++eb){
        bf16x8 bq = *(const bf16x8*)&Qt[(eb * 16 + c) * 72 + kk * 32 + g * 8];
        acc[eb] = __builtin_amdgcn_mfma_f32_16x16x32_bf16(av, bq, acc[eb], 0, 0, 0);
      }
    }
  }
  #pragma unroll
  for (int eb = 0; eb < 4; ++eb)
    #pragma unroll
    for (int r = 0; r < 4; ++r){
      int d = w * 16 + g * 4 + r, e = eb * 16 + c;
      Bp[(((size_t)sp * 16 + h) * 64 + d) * 64 + e] = acc[eb][r];
    }
}

// ---------------- reduce 8 partials -> Bt bf16 ----------------
__global__ __launch_bounds__(256) void k_bred(const float* __restrict__ Bp, u16* __restrict__ Bt){
  int i = blockIdx.x * 256 + threadIdx.x;   // 65536 total
  float s = 0.f;
  #pragma unroll
  for (int j = 0; j < 8; ++j) s += Bp[(size_t)j * 65536 + i];
  Bt[i] = f2bf(s * 0.125f);
}

// swizzled u16-index within a [rows][64] u16 LDS tile: XOR byte-bits 4-6 with row&7
__device__ __forceinline__ int swz(int row, int colbyte){
  return row * 64 + (((colbyte) ^ ((row & 7) << 4)) >> 1);
}

// ---------------- 128x128 bf16 MFMA GEMM, A[MxK] @ B^T (B given [N][K]) ----------------
// Per-operand staging: f32 source -> reg-load + cast + swizzled ds_write;
// bf16 source -> global_load_lds (linear dest, pre-swizzled source chunk).
// m97 single-buffer 2-barrier loop. EPI=0: scatter to qb bf16; EPI=1: C f32 + bias.
template<int A_F32, int B_F32, int EPI>
__global__ __launch_bounds__(256) void k_gemm(const void* __restrict__ A_, const void* __restrict__ B_,
                                              void* __restrict__ Cv, const float* __restrict__ bias,
                                              int M, int N, int K){
  int nbn = N >> 7;
  int ii = (int)blockIdx.x;
  int sw = (ii & 7) * 64 + (ii >> 3);      // XCD-contiguous chunks (512 = 8*64 blocks)
  int bm = sw / nbn, bn = sw % nbn;
  int tid = threadIdx.x, lane = tid & 63, wid = tid >> 6;
  int wr = wid >> 1, wc = wid & 1, g = lane >> 4, c = lane & 15;
  __shared__ u16 As[128 * 64];
  __shared__ u16 Bs[128 * 64];
  // gl_lds slots: slot=(wid*4+p)*64+lane; row=slot>>3, chunk c8=slot&7.
  // Linear dest = slot*8 u16; source chunk pre-swizzled: c8 ^ (row&7).
  int srow[4], scol[4], sdst[4];
  #pragma unroll
  for (int p = 0; p < 4; ++p){
    int slot = (wid * 4 + p) * 64 + lane;
    int row = slot >> 3, c8 = slot & 7;
    srow[p] = row;
    scol[p] = (c8 ^ (row & 7)) * 8;
    sdst[p] = slot * 8;
  }
  f32x4 zero = {0.f, 0.f, 0.f, 0.f};
  f32x4 acc[4][4];
  #pragma unroll
  for (int m = 0; m < 4; ++m)
    #pragma unroll
    for (int n = 0; n < 4; ++n) acc[m][n] = zero;
  for (int kt = 0; kt < K; kt += 64){
    __syncthreads();    // prev compute done reading LDS
    // async paths first (loads fly while reg paths execute)
    if (!A_F32){
      const u16* A = (const u16*)A_;
      #pragma unroll
      for (int p = 0; p < 4; ++p)
        gl_lds16(A + (size_t)(bm * 128 + srow[p]) * K + kt + scol[p], &As[sdst[p]]);
    }
    if (!B_F32){
      const u16* B = (const u16*)B_;
      #pragma unroll
      for (int p = 0; p < 4; ++p)
        gl_lds16(B + (size_t)(bn * 128 + srow[p]) * K + kt + scol[p], &Bs[sdst[p]]);
    }
    if (A_F32){
      const float* A = (const float*)A_;
      #pragma unroll
      for (int p = 0; p < 4; ++p){
        int ci = tid + p * 256;
        int row = ci >> 3, c8 = ci & 7;
        const float* src = A + (size_t)(bm * 128 + row) * K + kt + c8 * 8;
        f32x4 v0 = *(const f32x4*)src;
        f32x4 v1 = *(const f32x4*)(src + 4);
        union { u16 u[8]; i32x4 v; } pk;
        #pragma unroll
        for (int j = 0; j < 4; ++j){ pk.u[j] = f2bf_fast(v0[j]); pk.u[4 + j] = f2bf_fast(v1[j]); }
        *(i32x4*)&As[swz(row, c8 * 16)] = pk.v;
      }
    }
    if (B_F32){
      const float* B = (const float*)B_;
      #pragma unroll
      for (int p = 0; p < 4; ++p){
        int ci = tid + p * 256;
        int row = ci >> 3, c8 = ci & 7;
        const float* src = B + (size_t)(bn * 128 + row) * K + kt + c8 * 8;
        f32x4 v0 = *(const f32x4*)src;
        f32x4 v1 = *(const f32x4*)(src + 4);
        union { u16 u[8]; i32x4 v; } pk;
        #pragma unroll
        for (int j = 0; j < 4; ++j){ pk.u[j] = f2bf_fast(v0[j]); pk.u[4 + j] = f2bf_fast(v1[j]); }
        *(i32x4*)&Bs[swz(row, c8 * 16)] = pk.v;
      }
    }
    __syncthreads();    // drains vmcnt/lgkm -> LDS ready (m97 pattern)
    #pragma unroll
    for (int kk = 0; kk < 2; ++kk){
      bf16x8 af[4], bfr[4];
      #pragma unroll
      for (int m = 0; m < 4; ++m){
        int row = wr * 64 + m * 16 + c;
        af[m] = *(const bf16x8*)&As[swz(row, kk * 64 + g * 16)];
      }
      #pragma unroll
      for (int n = 0; n < 4; ++n){
        int row = wc * 64 + n * 16 + c;
        bfr[n] = *(const bf16x8*)&Bs[swz(row, kk * 64 + g * 16)];
      }
      #pragma unroll
      for (int m = 0; m < 4; ++m)
        #pragma unroll
        for (int n = 0; n < 4; ++n)
          acc[m][n] = __builtin_amdgcn_mfma_f32_16x16x32_bf16(af[m], bfr[n], acc[m][n], 0, 0, 0);
    }
  }
  #pragma unroll
  for (int m = 0; m < 4; ++m)
    #pragma unroll
    for (int n = 0; n < 4; ++n)
      #pragma unroll
      for (int r = 0; r < 4; ++r){
        int row = bm * 128 + wr * 64 + m * 16 + g * 4 + r;
        int col = bn * 128 + wc * 64 + n * 16 + c;
        float v = acc[m][n][r];
        if (EPI == 0){
          int t = row >> 3, b = row & 7, hh = col >> 6, dd = col & 63;
          ((u16*)Cv)[(((size_t)(b * H_ + hh)) * T_ + t) * HD_ + dd] = f2bf(v);
        } else {
          ((float*)Cv)[(size_t)row * N + col] = v + bias[col];
        }
      }
}

// ---------------- u^T = B_h^T q^T per (bh, 64-t tile); also scaled q_sq. 1 wave. ----------------
__global__ __launch_bounds__(64) void k_u(const u16* __restrict__ qb, const u16* __restrict__ Bt,
                                          u16* __restrict__ ubt, float* __restrict__ qsq){
  int bh = blockIdx.x >> 4, tt = blockIdx.x & 15;
  int h = bh & 15, t0 = tt * 64;
  int lane = threadIdx.x, g = lane >> 4, c = lane & 15;
  const float QS_SCALE = 0.125f * 1.44269504088896340736f;
  bf16x8 af[4][2], bq[4][2];
  #pragma unroll
  for (int mf = 0; mf < 4; ++mf)
    #pragma unroll
    for (int kk = 0; kk < 2; ++kk)
      af[mf][kk] = *(const bf16x8*)(Bt + ((size_t)(h * 64 + mf * 16 + c)) * 64 + kk * 32 + g * 8);
  #pragma unroll
  for (int nf = 0; nf < 4; ++nf)
    #pragma unroll
    for (int kk = 0; kk < 2; ++kk)
      bq[nf][kk] = *(const bf16x8*)(qb + ((size_t)(bh * 1024 + t0 + nf * 16 + c)) * 64 + kk * 32 + g * 8);
  // q_sq from the same bf16 q; prescaled by 0.125*log2(e)
  #pragma unroll
  for (int nf = 0; nf < 4; ++nf){
    float ss = 0.f;
    #pragma unroll
    for (int kk = 0; kk < 2; ++kk)
      #pragma unroll
      for (int j = 0; j < 8; ++j){ float f = bf2f((u16)bq[nf][kk][j]); ss = fmaf(f, f, ss); }
    ss += __shfl_xor(ss, 16);
    ss += __shfl_xor(ss, 32);
    if (lane < 16) qsq[(size_t)bh * 1024 + t0 + nf * 16 + lane] = ss * QS_SCALE;
  }
  f32x4 zero = {0.f, 0.f, 0.f, 0.f};
  f32x4 acc[4][4];
  #pragma unroll
  for (int mf = 0; mf < 4; ++mf)
    #pragma unroll
    for (int nf = 0; nf < 4; ++nf) acc[mf][nf] = zero;
  #pragma unroll
  for (int kk = 0; kk < 2; ++kk)
    #pragma unroll
    for (int mf = 0; mf < 4; ++mf)
      #pragma unroll
      for (int nf = 0; nf < 4; ++nf)
        acc[mf][nf] = __builtin_amdgcn_mfma_f32_16x16x32_bf16(af[mf][kk], bq[nf][kk], acc[mf][nf], 0, 0, 0);
  #pragma unroll
  for (int mf = 0; mf < 4; ++mf)
    #pragma unroll
    for (int nf = 0; nf < 4; ++nf)
      #pragma unroll
      for (int r = 0; r < 4; ++r)
        ubt[((size_t)(bh * 64 + mf * 16 + g * 4 + r)) * 1024 + t0 + nf * 16 + c] = f2bf(acc[mf][nf][r]);
}

// ---------------- L2 attention: TBLK=128, dbuf gl_lds staging, m97 single-drain schedule ----------------
// (round-10 version, 54.4 us proven) prologue: issue gl_lds(buf0). Loop: __syncthreads
// (drains vmcnt -> cur buf ready; all waves done reading buf^1) -> issue gl_lds(buf^1, st+1)
// -> compute(buf). Loads overlap the full compute phase. qsq panel staged once.
__global__ __launch_bounds__(256, 4) void k_attn(const u16* __restrict__ qb, const u16* __restrict__ ubt,
                                                 const float* __restrict__ qsq, u16* __restrict__ obm){
  int i = (int)blockIdx.x;
  // XCD grouping: XCD (i&7) owns bh in [16*(i&7), ...+16), all 8 t-tiles.
  int bh = ((i & 7) << 4) + (i >> 6);
  int tt = (i >> 3) & 7;
  int b = bh >> 4, h = bh & 15;
  int tid = threadIdx.x, w = tid >> 6, lane = tid & 63;
  int lo = lane & 31, hi = lane >> 5;
  __shared__ u16 Kl[2][64 * 64];
  __shared__ u16 Ul[2][64 * 64];
  __shared__ float Qs[1024];
  const float C1 = 0.25f * 1.44269504088896340736f;
  int t0 = tt * 128 + w * 32;
  const u16* qbh = qb + (size_t)bh * 65536;    // [t][64]
  const u16* ubh = ubt + (size_t)bh * 65536;   // [e][1024]
  const float* qsb = qsq + (size_t)bh * 1024;
  // stage the whole scaled-qsq panel once (4KB)
  *(f32x4*)&Qs[tid * 4] = *(const f32x4*)(qsb + tid * 4);
  // Q B-fragment (col=t=lo, k=d): 4 K=16 slices
  bf16x8 qB[4];
  #pragma unroll
  for (int kd = 0; kd < 4; ++kd)
    qB[kd] = *(const bf16x8*)(qbh + (t0 + lo) * 64 + kd * 16 + hi * 8);
  f32x16 o0 = {0,0,0,0,0,0,0,0,0,0,0,0,0,0,0,0};
  f32x16 o1 = {0,0,0,0,0,0,0,0,0,0,0,0,0,0,0,0};
  const f32x16 zero16 = {0,0,0,0,0,0,0,0,0,0,0,0,0,0,0,0};
  float l_c = 0.f;
  // gload slots: per wave 2 calls per operand; slot=(w*2+j)*64+lane -> row=slot>>3, c8=slot&7
  int slot0 = (w * 2 + 0) * 64 + lane, slot1 = (w * 2 + 1) * 64 + lane;
  int r0 = slot0 >> 3, sc0 = ((slot0 & 7) ^ (r0 & 7)) * 8;   // pre-swizzled source chunk
  int r1 = slot1 >> 3, sc1 = ((slot1 & 7) ^ (r1 & 7)) * 8;
  int d0 = (w * 2 + 0) * 512, d1 = (w * 2 + 1) * 512;
  // prologue: issue tile-0 loads into buf 0
  gl_lds16(qbh + r0 * 64 + sc0, &Kl[0][d0]);
  gl_lds16(qbh + r1 * 64 + sc1, &Kl[0][d1]);
  gl_lds16(ubh + (size_t)r0 * 1024 + sc0, &Ul[0][d0]);
  gl_lds16(ubh + (size_t)r1 * 1024 + sc1, &Ul[0][d1]);
  int cur = 0;
  for (int st = 0; st < 16; ++st){
    int s0 = st * 64;
    __syncthreads();   // drains vmcnt(0): buf[cur] landed (full round in flight); all waves past buf[cur^1] reads
    if (st < 15){
      int s1 = s0 + 64;
      int nb = cur ^ 1;
      gl_lds16(qbh + (s1 + r0) * 64 + sc0, &Kl[nb][d0]);
      gl_lds16(qbh + (s1 + r1) * 64 + sc1, &Kl[nb][d1]);
      gl_lds16(ubh + (size_t)r0 * 1024 + s1 + sc0, &Ul[nb][d0]);
      gl_lds16(ubh + (size_t)r1 * 1024 + s1 + sc1, &Ul[nb][d1]);
    }
    const u16* Kc = &Kl[cur][0];
    const u16* Uc = &Ul[cur][0];
    #pragma unroll
    for (int ts = 0; ts < 2; ++ts){
      f32x16 sf = zero16;
      __builtin_amdgcn_s_setprio(1);
      #pragma unroll
      for (int kd = 0; kd < 4; ++kd){
        bf16x8 kA = *(const bf16x8*)&Kc[swz(ts * 32 + lo, kd * 32 + hi * 16)];
        sf = __builtin_amdgcn_mfma_f32_32x32x16_bf16(kA, qB[kd], sf, 0, 0, 0);
      }
      __builtin_amdgcn_s_setprio(0);
      f32x4 qs_[4];
      #pragma unroll
      for (int q = 0; q < 4; ++q)
        qs_[q] = *(const f32x4*)&Qs[s0 + ts * 32 + q * 8 + hi * 4];
      float p[16];
      #pragma unroll
      for (int r = 0; r < 16; ++r)
        p[r] = exp2_raw(fmaf(sf[r], C1, -qs_[r >> 2][r & 3]));
      float sA = ((p[0] + p[1]) + (p[2] + p[3])) + ((p[4] + p[5]) + (p[6] + p[7]));
      float sB = ((p[8] + p[9]) + (p[10] + p[11])) + ((p[12] + p[13]) + (p[14] + p[15]));
      l_c += sA + sB;
      u32 W[8];
      #pragma unroll
      for (int q = 0; q < 8; ++q)
        W[q] = ((u32)f2bf_fast(p[2 * q + 1]) << 16) | (u32)f2bf_fast(p[2 * q]);
      // PV for this ts: k-slices m_g = ts*2 + {0,1}
      #pragma unroll
      for (int ml = 0; ml < 2; ++ml){
        int m_g = ts * 2 + ml;
        int base = ml * 4;
        i32x2 sw0 = __builtin_amdgcn_permlane32_swap((int)W[base + 0], (int)W[base + 2], false, false);
        i32x2 sw1 = __builtin_amdgcn_permlane32_swap((int)W[base + 1], (int)W[base + 3], false, false);
        union { u32 wd[4]; bf16x8 v; } pa;
        pa.wd[0] = (u32)sw0[0]; pa.wd[1] = (u32)sw1[0]; pa.wd[2] = (u32)sw0[1]; pa.wd[3] = (u32)sw1[1];
        bf16x8 u0 = *(const bf16x8*)&Uc[swz(lo, m_g * 32 + hi * 16)];
        bf16x8 u1 = *(const bf16x8*)&Uc[swz(32 + lo, m_g * 32 + hi * 16)];
        __builtin_amdgcn_s_setprio(1);
        o0 = __builtin_amdgcn_mfma_f32_32x32x16_bf16(pa.v, u0, o0, 0, 0, 0);
        o1 = __builtin_amdgcn_mfma_f32_32x32x16_bf16(pa.v, u1, o1, 0, 0, 0);
        __builtin_amdgcn_s_setprio(0);
      }
    }
    cur ^= 1;
  }
  // l: combine the two hi-halves; lane j then holds l for t = j&31
  l_c += __shfl_xor(l_c, 32);
  float inv = 1.0f / l_c;
  #pragma unroll
  for (int r = 0; r < 16; ++r){
    int tr = (r & 3) + 8 * (r >> 2) + 4 * hi;
    float invr = __shfl(inv, tr);
    size_t rowb = ((size_t)((t0 + tr) * 8 + b)) * 1024 + h * 64;
    obm[rowb + lo] = f2bf(o0[r] * invr);
    obm[rowb + 32 + lo] = f2bf(o1[r] * invr);
  }
}

extern "C" void kernel_launch(void* const* d_in, const int* in_sizes, int n_in,
                              void* d_out, int out_size, void* d_ws, size_t ws_size,
                              hipStream_t stream) {
  const float* x   = (const float*)d_in[0];
  const float* qw  = (const float*)d_in[1];
  const float* vw  = (const float*)d_in[2];
  const float* ow  = (const float*)d_in[3];
  const float* ob_bias = (const float*)d_in[4];
  float* out = (float*)d_out;

  // d_out (32 MiB) doubles as scratch:
  //  - Bp partials (2 MiB) at d_out front, consumed by k_bred before GEMM1 writes qb there
  //  - qb (16 MiB) + ubt (16 MiB) fill it afterwards; all dead before GEMM2 writes `out`.
  float* Bp = (float*)d_out;
  u16* qb  = (u16*)d_out;                                     // [bh][t][d]  16 MiB
  u16* ubt = (u16*)((char*)d_out + (size_t)16 * 1024 * 1024); // [bh][d][t]  16 MiB

  char* ws = (char*)d_ws;
  size_t off = 0;
  auto alloc = [&](size_t bytes) -> void* {
    void* p = ws + off;
    off += (bytes + 255) & ~(size_t)255;
    return p;
  };
  u16*   wqt = (u16*)  alloc((size_t)1024 * 1024 * 2);   // Wq^T bf16 [n][m]   2 MiB
  u16*   obm = (u16*)  alloc((size_t)8192 * 1024 * 2);   // attn out bf16     16 MiB
  float* qsq = (float*)alloc((size_t)128 * 1024 * 4);    // scaled |q|^2     0.5 MiB
  u16*   Bt  = (u16*)  alloc((size_t)16 * 64 * 64 * 2);  // B_h^T bf16      0.125 MiB

  k_bmatp<<<128, 256, 0, stream>>>(qw, vw, Bp);
  k_bred<<<256, 256, 0, stream>>>(Bp, Bt);
  k_wqt<<<dim3(16, 16), 256, 0, stream>>>(qw, wqt);
  // GEMM1: q = x @ Wq  (A = x f32 reg-cast staging, B = Wq^T bf16 gl_lds) -> qb scatter
  k_gemm<1, 0, 0><<<512, 256, 0, stream>>>(x, wqt, qb, nullptr, 8192, 1024, 1024);
  k_u<<<2048, 64, 0, stream>>>(qb, Bt, ubt, qsq);
  k_attn<<<1024, 256, 0, stream>>>(qb, ubt, qsq, obm);
  // GEMM2: out = obm @ out_w^T + b  (A = obm bf16 gl_lds, B = out_w f32 reg-cast)
  k_gemm<0, 1, 1><<<512, 256, 0, stream>>>(obm, ow, out, ob_bias, 8192, 1024, 1024);
}

// Round 15
// 127.838 us; speedup vs baseline: 1.1863x; 1.0613x over previous
//
#include <hip/hip_runtime.h>
#include <hip/hip_bf16.h>

#define T_ 1024
#define N_ 8
#define D_ 1024
#define H_ 16
#define HD_ 64

typedef __attribute__((ext_vector_type(8))) short bf16x8;
typedef __attribute__((ext_vector_type(4))) float f32x4;
typedef __attribute__((ext_vector_type(16))) float f32x16;
typedef __attribute__((ext_vector_type(4))) int i32x4;
typedef __attribute__((ext_vector_type(2))) int i32x2;
typedef unsigned short u16;
typedef unsigned int u32;

__device__ __forceinline__ float bf2f(u16 u){
  union { float f; unsigned int i; } v; v.i = ((unsigned int)u) << 16; return v.f;
}
__device__ __forceinline__ u16 f2bf(float f){
  union { float f; unsigned int i; } v; v.f = f;
  unsigned int r = v.i + 0x7FFFu + ((v.i >> 16) & 1u);
  return (u16)(r >> 16);
}
__device__ __forceinline__ u16 f2bf_fast(float f){
  __hip_bfloat16 h = __float2bfloat16(f);   // RNE; compiler packs pairs into v_cvt_pk_bf16_f32
  return *reinterpret_cast<u16*>(&h);
}
// raw v_exp_f32: args are well inside normal range (p<=e^15), skip libm fixup tail
__device__ __forceinline__ float exp2_raw(float x){
  float r;
  asm("v_exp_f32 %0, %1" : "=v"(r) : "v"(x));
  return r;
}
// async global->LDS, 16B per lane, dest = wave-uniform base + lane*16
__device__ __forceinline__ void gl_lds16(const u16* g, u16* l){
  __builtin_amdgcn_global_load_lds(
      (const __attribute__((address_space(1))) unsigned int*)g,
      (__attribute__((address_space(3))) unsigned int*)(unsigned int)(unsigned long long)l,
      16, 0, 0);
}

// ---------------- transpose+cast Wq (D x D) -> Wqt[n][m] bf16 ----------------
__global__ __launch_bounds__(256) void k_wqt(const float* __restrict__ Wq, u16* __restrict__ Wqt){
  __shared__ float tld[64][65];
  int m0 = blockIdx.x * 64, n0 = blockIdx.y * 64;
  int col = threadIdx.x & 63, rq = threadIdx.x >> 6;
  #pragma unroll
  for (int p = 0; p < 16; ++p){
    int row = rq * 16 + p;
    tld[row][col] = Wq[(size_t)(m0 + row) * D_ + n0 + col];
  }
  __syncthreads();
  #pragma unroll
  for (int p = 0; p < 16; ++p){
    int row = rq * 16 + p;
    Wqt[(size_t)(n0 + row) * D_ + m0 + col] = f2bf(tld[col][row]);
  }
}

// ---------------- Bp[sp][h][d][e] partials of sum_m qw[m,h,e]*vw[m,h,d] (MFMA split-K) ----------------
__global__ __launch_bounds__(256) void k_bmatp(const float* __restrict__ qw, const float* __restrict__ vw,
                                               float* __restrict__ Bp){
  int h = (int)blockIdx.x >> 3, sp = (int)blockIdx.x & 7;
  int tid = threadIdx.x, lane = tid & 63, w = tid >> 6;
  int g = lane >> 4, c = lane & 15;
  __shared__ u16 Qt[64 * 72];  // [e][m] transposed, bf16
  __shared__ u16 Vt[64 * 72];  // [d][m]
  f32x4 zero = {0.f, 0.f, 0.f, 0.f};
  f32x4 acc[4];
  #pragma unroll
  for (int eb = 0; eb < 4; ++eb) acc[eb] = zero;
  int m = tid >> 2, cg = tid & 3;
  for (int mt = sp * 128; mt < sp * 128 + 128; mt += 64){
    __syncthreads();
    #pragma unroll
    for (int q = 0; q < 4; ++q){
      int e0 = cg * 16 + q * 4;
      f32x4 vq = *(const f32x4*)(qw + (size_t)(mt + m) * D_ + h * 64 + e0);
      f32x4 vv = *(const f32x4*)(vw + (size_t)(mt + m) * D_ + h * 64 + e0);
      #pragma unroll
      for (int j = 0; j < 4; ++j){
        Qt[(e0 + j) * 72 + m] = f2bf_fast(vq[j]);
        Vt[(e0 + j) * 72 + m] = f2bf_fast(vv[j]);
      }
    }
    __syncthreads();
    #pragma unroll
    for (int kk = 0; kk < 2; ++kk){
      bf16x8 av = *(const bf16x8*)&Vt[(w * 16 + c) * 72 + kk * 32 + g * 8];
      #pragma unroll
      for (int eb = 0; eb < 4; ++eb){
        bf16x8 bq = *(const bf16x8*)&Qt[(eb * 16 + c) * 72 + kk * 32 + g * 8];
        acc[eb] = __builtin_amdgcn_mfma_f32_16x16x32_bf16(av, bq, acc[eb], 0, 0, 0);
      }
    }
  }
  #pragma unroll
  for (int eb = 0; eb < 4; ++eb)
    #pragma unroll
    for (int r = 0; r < 4; ++r){
      int d = w * 16 + g * 4 + r, e = eb * 16 + c;
      Bp[(((size_t)sp * 16 + h) * 64 + d) * 64 + e] = acc[eb][r];
    }
}

// ---------------- reduce 8 partials -> Bt bf16 ----------------
__global__ __launch_bounds__(256) void k_bred(const float* __restrict__ Bp, u16* __restrict__ Bt){
  int i = blockIdx.x * 256 + threadIdx.x;   // 65536 total
  float s = 0.f;
  #pragma unroll
  for (int j = 0; j < 8; ++j) s += Bp[(size_t)j * 65536 + i];
  Bt[i] = f2bf(s * 0.125f);
}

// swizzled u16-index within a [rows][64] u16 LDS tile: XOR byte-bits 4-6 with row&7
__device__ __forceinline__ int swz(int row, int colbyte){
  return row * 64 + (((colbyte) ^ ((row & 7) << 4)) >> 1);
}

// ---------------- 128x128 bf16 MFMA GEMM, A[MxK] @ B^T (B given [N][K]) ----------------
// Double-buffered (r10-attn schedule): prologue stages tile 0; per phase:
// barrier (buf[cur] landed — full phase in flight; prev reads done) -> issue next-tile
// staging (bf16 via global_load_lds linear-dest/pre-swizzled-src; f32 via T14 split:
// reg loads issued now, ds_write after compute) -> compute(buf[cur]) -> late ds_write.
// EPI=0: scatter to qb bf16; EPI=1: C f32 + bias.
template<int A_F32, int B_F32, int EPI>
__global__ __launch_bounds__(256) void k_gemm(const void* __restrict__ A_, const void* __restrict__ B_,
                                              void* __restrict__ Cv, const float* __restrict__ bias,
                                              int M, int N, int K){
  int nbn = N >> 7;
  int ii = (int)blockIdx.x;
  int sw = (ii & 7) * 64 + (ii >> 3);      // XCD-contiguous chunks (512 = 8*64 blocks)
  int bm = sw / nbn, bn = sw % nbn;
  int tid = threadIdx.x, lane = tid & 63, wid = tid >> 6;
  int wr = wid >> 1, wc = wid & 1, g = lane >> 4, c = lane & 15;
  __shared__ u16 As[2][128 * 64];
  __shared__ u16 Bs[2][128 * 64];
  // gl_lds slots: slot=(wid*4+p)*64+lane; row=slot>>3, chunk c8=slot&7.
  int srow[4], scol[4], sdst[4];
  #pragma unroll
  for (int p = 0; p < 4; ++p){
    int slot = (wid * 4 + p) * 64 + lane;
    int row = slot >> 3, c8 = slot & 7;
    srow[p] = row;
    scol[p] = (c8 ^ (row & 7)) * 8;   // pre-swizzled source chunk
    sdst[p] = slot * 8;               // linear dest
  }
  // reg-path (f32) slots: ci = tid + p*256 -> row=ci>>3, c8=ci&7
  int rrow[4], rc8[4];
  #pragma unroll
  for (int p = 0; p < 4; ++p){
    int ci = tid + p * 256;
    rrow[p] = ci >> 3; rc8[p] = ci & 7;
  }
  f32x4 zero = {0.f, 0.f, 0.f, 0.f};
  f32x4 acc[4][4];
  #pragma unroll
  for (int m = 0; m < 4; ++m)
    #pragma unroll
    for (int n = 0; n < 4; ++n) acc[m][n] = zero;
  f32x4 rA[4][2], rB[4][2];
  const u16* Ab = (const u16*)A_;
  const u16* Bb = (const u16*)B_;
  const float* Af = (const float*)A_;
  const float* Bf = (const float*)B_;
  // ---- prologue: stage tile 0 into buf 0
  if (!A_F32){
    #pragma unroll
    for (int p = 0; p < 4; ++p)
      gl_lds16(Ab + (size_t)(bm * 128 + srow[p]) * K + scol[p], &As[0][sdst[p]]);
  }
  if (!B_F32){
    #pragma unroll
    for (int p = 0; p < 4; ++p)
      gl_lds16(Bb + (size_t)(bn * 128 + srow[p]) * K + scol[p], &Bs[0][sdst[p]]);
  }
  if (A_F32){
    #pragma unroll
    for (int p = 0; p < 4; ++p){
      const float* src = Af + (size_t)(bm * 128 + rrow[p]) * K + rc8[p] * 8;
      rA[p][0] = *(const f32x4*)src;
      rA[p][1] = *(const f32x4*)(src + 4);
    }
    #pragma unroll
    for (int p = 0; p < 4; ++p){
      union { u16 u[8]; i32x4 v; } pk;
      #pragma unroll
      for (int j = 0; j < 4; ++j){ pk.u[j] = f2bf_fast(rA[p][0][j]); pk.u[4 + j] = f2bf_fast(rA[p][1][j]); }
      *(i32x4*)&As[0][swz(rrow[p], rc8[p] * 16)] = pk.v;
    }
  }
  if (B_F32){
    #pragma unroll
    for (int p = 0; p < 4; ++p){
      const float* src = Bf + (size_t)(bn * 128 + rrow[p]) * K + rc8[p] * 8;
      rB[p][0] = *(const f32x4*)src;
      rB[p][1] = *(const f32x4*)(src + 4);
    }
    #pragma unroll
    for (int p = 0; p < 4; ++p){
      union { u16 u[8]; i32x4 v; } pk;
      #pragma unroll
      for (int j = 0; j < 4; ++j){ pk.u[j] = f2bf_fast(rB[p][0][j]); pk.u[4 + j] = f2bf_fast(rB[p][1][j]); }
      *(i32x4*)&Bs[0][swz(rrow[p], rc8[p] * 16)] = pk.v;
    }
  }
  int NT = K >> 6;
  int cur = 0;
  for (int st = 0; st < NT; ++st){
    __syncthreads();   // buf[cur] ready (gl_lds drained / ds_writes visible); prev reads of buf[cur^1] done
    int kt1 = (st + 1) * 64;
    int nb = cur ^ 1;
    if (st + 1 < NT){
      if (!A_F32){
        #pragma unroll
        for (int p = 0; p < 4; ++p)
          gl_lds16(Ab + (size_t)(bm * 128 + srow[p]) * K + kt1 + scol[p], &As[nb][sdst[p]]);
      }
      if (!B_F32){
        #pragma unroll
        for (int p = 0; p < 4; ++p)
          gl_lds16(Bb + (size_t)(bn * 128 + srow[p]) * K + kt1 + scol[p], &Bs[nb][sdst[p]]);
      }
      if (A_F32){
        #pragma unroll
        for (int p = 0; p < 4; ++p){
          const float* src = Af + (size_t)(bm * 128 + rrow[p]) * K + kt1 + rc8[p] * 8;
          rA[p][0] = *(const f32x4*)src;
          rA[p][1] = *(const f32x4*)(src + 4);
        }
      }
      if (B_F32){
        #pragma unroll
        for (int p = 0; p < 4; ++p){
          const float* src = Bf + (size_t)(bn * 128 + rrow[p]) * K + kt1 + rc8[p] * 8;
          rB[p][0] = *(const f32x4*)src;
          rB[p][1] = *(const f32x4*)(src + 4);
        }
      }
    }
    // ---- compute on buf[cur]; f32-path loads fly over this section
    #pragma unroll
    for (int kk = 0; kk < 2; ++kk){
      bf16x8 af[4], bfr[4];
      #pragma unroll
      for (int m = 0; m < 4; ++m){
        int row = wr * 64 + m * 16 + c;
        af[m] = *(const bf16x8*)&As[cur][swz(row, kk * 64 + g * 16)];
      }
      #pragma unroll
      for (int n = 0; n < 4; ++n){
        int row = wc * 64 + n * 16 + c;
        bfr[n] = *(const bf16x8*)&Bs[cur][swz(row, kk * 64 + g * 16)];
      }
      #pragma unroll
      for (int m = 0; m < 4; ++m)
        #pragma unroll
        for (int n = 0; n < 4; ++n)
          acc[m][n] = __builtin_amdgcn_mfma_f32_16x16x32_bf16(af[m], bfr[n], acc[m][n], 0, 0, 0);
    }
    // ---- late ds_write of the f32-path tile (loads landed during compute)
    if (st + 1 < NT){
      if (A_F32){
        #pragma unroll
        for (int p = 0; p < 4; ++p){
          union { u16 u[8]; i32x4 v; } pk;
          #pragma unroll
          for (int j = 0; j < 4; ++j){ pk.u[j] = f2bf_fast(rA[p][0][j]); pk.u[4 + j] = f2bf_fast(rA[p][1][j]); }
          *(i32x4*)&As[nb][swz(rrow[p], rc8[p] * 16)] = pk.v;
        }
      }
      if (B_F32){
        #pragma unroll
        for (int p = 0; p < 4; ++p){
          union { u16 u[8]; i32x4 v; } pk;
          #pragma unroll
          for (int j = 0; j < 4; ++j){ pk.u[j] = f2bf_fast(rB[p][0][j]); pk.u[4 + j] = f2bf_fast(rB[p][1][j]); }
          *(i32x4*)&Bs[nb][swz(rrow[p], rc8[p] * 16)] = pk.v;
        }
      }
    }
    cur ^= 1;
  }
  #pragma unroll
  for (int m = 0; m < 4; ++m)
    #pragma unroll
    for (int n = 0; n < 4; ++n)
      #pragma unroll
      for (int r = 0; r < 4; ++r){
        int row = bm * 128 + wr * 64 + m * 16 + g * 4 + r;
        int col = bn * 128 + wc * 64 + n * 16 + c;
        float v = acc[m][n][r];
        if (EPI == 0){
          int t = row >> 3, b = row & 7, hh = col >> 6, dd = col & 63;
          ((u16*)Cv)[(((size_t)(b * H_ + hh)) * T_ + t) * HD_ + dd] = f2bf(v);
        } else {
          ((float*)Cv)[(size_t)row * N + col] = v + bias[col];
        }
      }
}

// ---------------- u^T = B_h^T q^T; 4 waves/block, wave w owns one 64-t tile ----------------
__global__ __launch_bounds__(256) void k_u(const u16* __restrict__ qb, const u16* __restrict__ Bt,
                                           u16* __restrict__ ubt, float* __restrict__ qsq){
  int blk = (int)blockIdx.x;            // 512 blocks
  int bh = blk >> 2;
  int w = threadIdx.x >> 6;
  int tt = (blk & 3) * 4 + w;
  int h = bh & 15, t0 = tt * 64;
  int lane = threadIdx.x & 63, g = lane >> 4, c = lane & 15;
  const float QS_SCALE = 0.125f * 1.44269504088896340736f;
  bf16x8 af[4][2], bq[4][2];
  #pragma unroll
  for (int mf = 0; mf < 4; ++mf)
    #pragma unroll
    for (int kk = 0; kk < 2; ++kk)
      af[mf][kk] = *(const bf16x8*)(Bt + ((size_t)(h * 64 + mf * 16 + c)) * 64 + kk * 32 + g * 8);
  #pragma unroll
  for (int nf = 0; nf < 4; ++nf)
    #pragma unroll
    for (int kk = 0; kk < 2; ++kk)
      bq[nf][kk] = *(const bf16x8*)(qb + ((size_t)(bh * 1024 + t0 + nf * 16 + c)) * 64 + kk * 32 + g * 8);
  // q_sq from the same bf16 q; prescaled by 0.125*log2(e)
  #pragma unroll
  for (int nf = 0; nf < 4; ++nf){
    float ss = 0.f;
    #pragma unroll
    for (int kk = 0; kk < 2; ++kk)
      #pragma unroll
      for (int j = 0; j < 8; ++j){ float f = bf2f((u16)bq[nf][kk][j]); ss = fmaf(f, f, ss); }
    ss += __shfl_xor(ss, 16);
    ss += __shfl_xor(ss, 32);
    if (lane < 16) qsq[(size_t)bh * 1024 + t0 + nf * 16 + lane] = ss * QS_SCALE;
  }
  f32x4 zero = {0.f, 0.f, 0.f, 0.f};
  f32x4 acc[4][4];
  #pragma unroll
  for (int mf = 0; mf < 4; ++mf)
    #pragma unroll
    for (int nf = 0; nf < 4; ++nf) acc[mf][nf] = zero;
  #pragma unroll
  for (int kk = 0; kk < 2; ++kk)
    #pragma unroll
    for (int mf = 0; mf < 4; ++mf)
      #pragma unroll
      for (int nf = 0; nf < 4; ++nf)
        acc[mf][nf] = __builtin_amdgcn_mfma_f32_16x16x32_bf16(af[mf][kk], bq[nf][kk], acc[mf][nf], 0, 0, 0);
  #pragma unroll
  for (int mf = 0; mf < 4; ++mf)
    #pragma unroll
    for (int nf = 0; nf < 4; ++nf)
      #pragma unroll
      for (int r = 0; r < 4; ++r)
        ubt[((size_t)(bh * 64 + mf * 16 + g * 4 + r)) * 1024 + t0 + nf * 16 + c] = f2bf(acc[mf][nf][r]);
}

// ---------------- L2 attention: TBLK=128, dbuf gl_lds staging, m97 single-drain schedule ----------------
// (round-10 version, 54.4 us proven)
__global__ __launch_bounds__(256, 4) void k_attn(const u16* __restrict__ qb, const u16* __restrict__ ubt,
                                                 const float* __restrict__ qsq, u16* __restrict__ obm){
  int i = (int)blockIdx.x;
  // XCD grouping: XCD (i&7) owns bh in [16*(i&7), ...+16), all 8 t-tiles.
  int bh = ((i & 7) << 4) + (i >> 6);
  int tt = (i >> 3) & 7;
  int b = bh >> 4, h = bh & 15;
  int tid = threadIdx.x, w = tid >> 6, lane = tid & 63;
  int lo = lane & 31, hi = lane >> 5;
  __shared__ u16 Kl[2][64 * 64];
  __shared__ u16 Ul[2][64 * 64];
  __shared__ float Qs[1024];
  const float C1 = 0.25f * 1.44269504088896340736f;
  int t0 = tt * 128 + w * 32;
  const u16* qbh = qb + (size_t)bh * 65536;    // [t][64]
  const u16* ubh = ubt + (size_t)bh * 65536;   // [e][1024]
  const float* qsb = qsq + (size_t)bh * 1024;
  // stage the whole scaled-qsq panel once (4KB)
  *(f32x4*)&Qs[tid * 4] = *(const f32x4*)(qsb + tid * 4);
  // Q B-fragment (col=t=lo, k=d): 4 K=16 slices
  bf16x8 qB[4];
  #pragma unroll
  for (int kd = 0; kd < 4; ++kd)
    qB[kd] = *(const bf16x8*)(qbh + (t0 + lo) * 64 + kd * 16 + hi * 8);
  f32x16 o0 = {0,0,0,0,0,0,0,0,0,0,0,0,0,0,0,0};
  f32x16 o1 = {0,0,0,0,0,0,0,0,0,0,0,0,0,0,0,0};
  const f32x16 zero16 = {0,0,0,0,0,0,0,0,0,0,0,0,0,0,0,0};
  float l_c = 0.f;
  // gload slots: per wave 2 calls per operand; slot=(w*2+j)*64+lane -> row=slot>>3, c8=slot&7
  int slot0 = (w * 2 + 0) * 64 + lane, slot1 = (w * 2 + 1) * 64 + lane;
  int r0 = slot0 >> 3, sc0 = ((slot0 & 7) ^ (r0 & 7)) * 8;   // pre-swizzled source chunk
  int r1 = slot1 >> 3, sc1 = ((slot1 & 7) ^ (r1 & 7)) * 8;
  int d0 = (w * 2 + 0) * 512, d1 = (w * 2 + 1) * 512;
  // prologue: issue tile-0 loads into buf 0
  gl_lds16(qbh + r0 * 64 + sc0, &Kl[0][d0]);
  gl_lds16(qbh + r1 * 64 + sc1, &Kl[0][d1]);
  gl_lds16(ubh + (size_t)r0 * 1024 + sc0, &Ul[0][d0]);
  gl_lds16(ubh + (size_t)r1 * 1024 + sc1, &Ul[0][d1]);
  int cur = 0;
  for (int st = 0; st < 16; ++st){
    int s0 = st * 64;
    __syncthreads();   // drains vmcnt(0): buf[cur] landed (full round in flight); all waves past buf[cur^1] reads
    if (st < 15){
      int s1 = s0 + 64;
      int nb = cur ^ 1;
      gl_lds16(qbh + (s1 + r0) * 64 + sc0, &Kl[nb][d0]);
      gl_lds16(qbh + (s1 + r1) * 64 + sc1, &Kl[nb][d1]);
      gl_lds16(ubh + (size_t)r0 * 1024 + s1 + sc0, &Ul[nb][d0]);
      gl_lds16(ubh + (size_t)r1 * 1024 + s1 + sc1, &Ul[nb][d1]);
    }
    const u16* Kc = &Kl[cur][0];
    const u16* Uc = &Ul[cur][0];
    #pragma unroll
    for (int ts = 0; ts < 2; ++ts){
      f32x16 sf = zero16;
      __builtin_amdgcn_s_setprio(1);
      #pragma unroll
      for (int kd = 0; kd < 4; ++kd){
        bf16x8 kA = *(const bf16x8*)&Kc[swz(ts * 32 + lo, kd * 32 + hi * 16)];
        sf = __builtin_amdgcn_mfma_f32_32x32x16_bf16(kA, qB[kd], sf, 0, 0, 0);
      }
      __builtin_amdgcn_s_setprio(0);
      f32x4 qs_[4];
      #pragma unroll
      for (int q = 0; q < 4; ++q)
        qs_[q] = *(const f32x4*)&Qs[s0 + ts * 32 + q * 8 + hi * 4];
      float p[16];
      #pragma unroll
      for (int r = 0; r < 16; ++r)
        p[r] = exp2_raw(fmaf(sf[r], C1, -qs_[r >> 2][r & 3]));
      float sA = ((p[0] + p[1]) + (p[2] + p[3])) + ((p[4] + p[5]) + (p[6] + p[7]));
      float sB = ((p[8] + p[9]) + (p[10] + p[11])) + ((p[12] + p[13]) + (p[14] + p[15]));
      l_c += sA + sB;
      u32 W[8];
      #pragma unroll
      for (int q = 0; q < 8; ++q)
        W[q] = ((u32)f2bf_fast(p[2 * q + 1]) << 16) | (u32)f2bf_fast(p[2 * q]);
      // PV for this ts: k-slices m_g = ts*2 + {0,1}
      #pragma unroll
      for (int ml = 0; ml < 2; ++ml){
        int m_g = ts * 2 + ml;
        int base = ml * 4;
        i32x2 sw0 = __builtin_amdgcn_permlane32_swap((int)W[base + 0], (int)W[base + 2], false, false);
        i32x2 sw1 = __builtin_amdgcn_permlane32_swap((int)W[base + 1], (int)W[base + 3], false, false);
        union { u32 wd[4]; bf16x8 v; } pa;
        pa.wd[0] = (u32)sw0[0]; pa.wd[1] = (u32)sw1[0]; pa.wd[2] = (u32)sw0[1]; pa.wd[3] = (u32)sw1[1];
        bf16x8 u0 = *(const bf16x8*)&Uc[swz(lo, m_g * 32 + hi * 16)];
        bf16x8 u1 = *(const bf16x8*)&Uc[swz(32 + lo, m_g * 32 + hi * 16)];
        __builtin_amdgcn_s_setprio(1);
        o0 = __builtin_amdgcn_mfma_f32_32x32x16_bf16(pa.v, u0, o0, 0, 0, 0);
        o1 = __builtin_amdgcn_mfma_f32_32x32x16_bf16(pa.v, u1, o1, 0, 0, 0);
        __builtin_amdgcn_s_setprio(0);
      }
    }
    cur ^= 1;
  }
  // l: combine the two hi-halves; lane j then holds l for t = j&31
  l_c += __shfl_xor(l_c, 32);
  float inv = 1.0f / l_c;
  #pragma unroll
  for (int r = 0; r < 16; ++r){
    int tr = (r & 3) + 8 * (r >> 2) + 4 * hi;
    float invr = __shfl(inv, tr);
    size_t rowb = ((size_t)((t0 + tr) * 8 + b)) * 1024 + h * 64;
    obm[rowb + lo] = f2bf(o0[r] * invr);
    obm[rowb + 32 + lo] = f2bf(o1[r] * invr);
  }
}

extern "C" void kernel_launch(void* const* d_in, const int* in_sizes, int n_in,
                              void* d_out, int out_size, void* d_ws, size_t ws_size,
                              hipStream_t stream) {
  const float* x   = (const float*)d_in[0];
  const float* qw  = (const float*)d_in[1];
  const float* vw  = (const float*)d_in[2];
  const float* ow  = (const float*)d_in[3];
  const float* ob_bias = (const float*)d_in[4];
  float* out = (float*)d_out;

  // d_out (32 MiB) doubles as scratch:
  //  - Bp partials (2 MiB) at d_out front, consumed by k_bred before GEMM1 writes qb there
  //  - qb (16 MiB) + ubt (16 MiB) fill it afterwards; all dead before GEMM2 writes `out`.
  float* Bp = (float*)d_out;
  u16* qb  = (u16*)d_out;                                     // [bh][t][d]  16 MiB
  u16* ubt = (u16*)((char*)d_out + (size_t)16 * 1024 * 1024); // [bh][d][t]  16 MiB

  char* ws = (char*)d_ws;
  size_t off = 0;
  auto alloc = [&](size_t bytes) -> void* {
    void* p = ws + off;
    off += (bytes + 255) & ~(size_t)255;
    return p;
  };
  u16*   wqt = (u16*)  alloc((size_t)1024 * 1024 * 2);   // Wq^T bf16 [n][m]   2 MiB
  u16*   obm = (u16*)  alloc((size_t)8192 * 1024 * 2);   // attn out bf16     16 MiB
  float* qsq = (float*)alloc((size_t)128 * 1024 * 4);    // scaled |q|^2     0.5 MiB
  u16*   Bt  = (u16*)  alloc((size_t)16 * 64 * 64 * 2);  // B_h^T bf16      0.125 MiB

  k_bmatp<<<128, 256, 0, stream>>>(qw, vw, Bp);
  k_bred<<<256, 256, 0, stream>>>(Bp, Bt);
  k_wqt<<<dim3(16, 16), 256, 0, stream>>>(qw, wqt);
  // GEMM1: q = x @ Wq  (A = x f32 T14 reg-path, B = Wq^T bf16 gl_lds; dbuf) -> qb scatter
  k_gemm<1, 0, 0><<<512, 256, 0, stream>>>(x, wqt, qb, nullptr, 8192, 1024, 1024);
  k_u<<<512, 256, 0, stream>>>(qb, Bt, ubt, qsq);
  k_attn<<<1024, 256, 0, stream>>>(qb, ubt, qsq, obm);
  // GEMM2: out = obm @ out_w^T + b  (A = obm bf16 gl_lds, B = out_w f32 T14 reg-path; dbuf)
  k_gemm<0, 1, 1><<<512, 256, 0, stream>>>(obm, ow, out, ob_bias, 8192, 1024, 1024);
}

// Round 16
// 121.794 us; speedup vs baseline: 1.2452x; 1.0496x over previous
//
#include <hip/hip_runtime.h>
#include <hip/hip_bf16.h>

#define T_ 1024
#define N_ 8
#define D_ 1024
#define H_ 16
#define HD_ 64

typedef __attribute__((ext_vector_type(8))) short bf16x8;
typedef __attribute__((ext_vector_type(2))) float f32x2;
typedef __attribute__((ext_vector_type(4))) float f32x4;
typedef __attribute__((ext_vector_type(16))) float f32x16;
typedef __attribute__((ext_vector_type(4))) int i32x4;
typedef __attribute__((ext_vector_type(2))) int i32x2;
typedef unsigned short u16;
typedef unsigned int u32;

__device__ __forceinline__ float bf2f(u16 u){
  union { float f; unsigned int i; } v; v.i = ((unsigned int)u) << 16; return v.f;
}
__device__ __forceinline__ u16 f2bf(float f){
  union { float f; unsigned int i; } v; v.f = f;
  unsigned int r = v.i + 0x7FFFu + ((v.i >> 16) & 1u);
  return (u16)(r >> 16);
}
__device__ __forceinline__ u16 f2bf_fast(float f){
  __hip_bfloat16 h = __float2bfloat16(f);   // RNE; compiler packs pairs into v_cvt_pk_bf16_f32
  return *reinterpret_cast<u16*>(&h);
}
// raw v_exp_f32: args are well inside normal range (p<=e^15), skip libm fixup tail
__device__ __forceinline__ float exp2_raw(float x){
  float r;
  asm("v_exp_f32 %0, %1" : "=v"(r) : "v"(x));
  return r;
}
// async global->LDS, 16B per lane, dest = wave-uniform base + lane*16
__device__ __forceinline__ void gl_lds16(const u16* g, u16* l){
  __builtin_amdgcn_global_load_lds(
      (const __attribute__((address_space(1))) unsigned int*)g,
      (__attribute__((address_space(3))) unsigned int*)(unsigned int)(unsigned long long)l,
      16, 0, 0);
}

// ---------------- fused pre-kernel: blocks 0-127 = bmatp; 128-383 = wqt ----------------
// bmatp: Bp[sp][h][d][e] partials of sum_m qw[m,h,e]*vw[m,h,d] (MFMA split-K)
// wqt: transpose+cast Wq (D x D) -> Wqt[n][m] bf16
__global__ __launch_bounds__(256) void k_pre(const float* __restrict__ qw, const float* __restrict__ vw,
                                             float* __restrict__ Bp, const float* __restrict__ Wq,
                                             u16* __restrict__ Wqt){
  __shared__ u16 Qt[64 * 72];
  __shared__ u16 Vt[64 * 72];
  __shared__ float tld[64][65];
  int blk = (int)blockIdx.x;
  int tid = threadIdx.x;
  if (blk < 128){
    int h = blk >> 3, sp = blk & 7;
    int lane = tid & 63, w = tid >> 6;
    int g = lane >> 4, c = lane & 15;
    f32x4 zero = {0.f, 0.f, 0.f, 0.f};
    f32x4 acc[4];
    #pragma unroll
    for (int eb = 0; eb < 4; ++eb) acc[eb] = zero;
    int m = tid >> 2, cg = tid & 3;
    for (int mt = sp * 128; mt < sp * 128 + 128; mt += 64){
      __syncthreads();
      #pragma unroll
      for (int q = 0; q < 4; ++q){
        int e0 = cg * 16 + q * 4;
        f32x4 vq = *(const f32x4*)(qw + (size_t)(mt + m) * D_ + h * 64 + e0);
        f32x4 vv = *(const f32x4*)(vw + (size_t)(mt + m) * D_ + h * 64 + e0);
        #pragma unroll
        for (int j = 0; j < 4; ++j){
          Qt[(e0 + j) * 72 + m] = f2bf_fast(vq[j]);
          Vt[(e0 + j) * 72 + m] = f2bf_fast(vv[j]);
        }
      }
      __syncthreads();
      #pragma unroll
      for (int kk = 0; kk < 2; ++kk){
        bf16x8 av = *(const bf16x8*)&Vt[(w * 16 + c) * 72 + kk * 32 + g * 8];
        #pragma unroll
        for (int eb = 0; eb < 4; ++eb){
          bf16x8 bq = *(const bf16x8*)&Qt[(eb * 16 + c) * 72 + kk * 32 + g * 8];
          acc[eb] = __builtin_amdgcn_mfma_f32_16x16x32_bf16(av, bq, acc[eb], 0, 0, 0);
        }
      }
    }
    #pragma unroll
    for (int eb = 0; eb < 4; ++eb)
      #pragma unroll
      for (int r = 0; r < 4; ++r){
        int d = w * 16 + g * 4 + r, e = eb * 16 + c;
        Bp[(((size_t)sp * 16 + h) * 64 + d) * 64 + e] = acc[eb][r];
      }
  } else {
    int b2 = blk - 128;
    int m0 = (b2 & 15) * 64, n0 = (b2 >> 4) * 64;
    int col = tid & 63, rq = tid >> 6;
    #pragma unroll
    for (int p = 0; p < 16; ++p){
      int row = rq * 16 + p;
      tld[row][col] = Wq[(size_t)(m0 + row) * D_ + n0 + col];
    }
    __syncthreads();
    #pragma unroll
    for (int p = 0; p < 16; ++p){
      int row = rq * 16 + p;
      Wqt[(size_t)(n0 + row) * D_ + m0 + col] = f2bf(tld[col][row]);
    }
  }
}

// ---------------- reduce 8 partials -> Bt bf16 ----------------
__global__ __launch_bounds__(256) void k_bred(const float* __restrict__ Bp, u16* __restrict__ Bt){
  int i = blockIdx.x * 256 + threadIdx.x;   // 65536 total
  float s = 0.f;
  #pragma unroll
  for (int j = 0; j < 8; ++j) s += Bp[(size_t)j * 65536 + i];
  Bt[i] = f2bf(s * 0.125f);
}

// swizzled u16-index within a [rows][64] u16 LDS tile: XOR byte-bits 4-6 with row&7
__device__ __forceinline__ int swz(int row, int colbyte){
  return row * 64 + (((colbyte) ^ ((row & 7) << 4)) >> 1);
}

// ---------------- 128x128 bf16 MFMA GEMM, A[MxK] @ B^T (B given [N][K]) ----------------
// Double-buffered (r10-attn schedule); bf16 operand via global_load_lds
// (linear dest, pre-swizzled src); f32 operand via T14 split (reg loads early,
// ds_write after compute). EPI=0: scatter to qb bf16; EPI=1: C f32 + bias.
template<int A_F32, int B_F32, int EPI>
__global__ __launch_bounds__(256) void k_gemm(const void* __restrict__ A_, const void* __restrict__ B_,
                                              void* __restrict__ Cv, const float* __restrict__ bias,
                                              int M, int N, int K){
  int nbn = N >> 7;
  int ii = (int)blockIdx.x;
  int sw = (ii & 7) * 64 + (ii >> 3);      // XCD-contiguous chunks (512 = 8*64 blocks)
  int bm = sw / nbn, bn = sw % nbn;
  int tid = threadIdx.x, lane = tid & 63, wid = tid >> 6;
  int wr = wid >> 1, wc = wid & 1, g = lane >> 4, c = lane & 15;
  __shared__ u16 As[2][128 * 64];
  __shared__ u16 Bs[2][128 * 64];
  int srow[4], scol[4], sdst[4];
  #pragma unroll
  for (int p = 0; p < 4; ++p){
    int slot = (wid * 4 + p) * 64 + lane;
    int row = slot >> 3, c8 = slot & 7;
    srow[p] = row;
    scol[p] = (c8 ^ (row & 7)) * 8;   // pre-swizzled source chunk
    sdst[p] = slot * 8;               // linear dest
  }
  int rrow[4], rc8[4];
  #pragma unroll
  for (int p = 0; p < 4; ++p){
    int ci = tid + p * 256;
    rrow[p] = ci >> 3; rc8[p] = ci & 7;
  }
  f32x4 zero = {0.f, 0.f, 0.f, 0.f};
  f32x4 acc[4][4];
  #pragma unroll
  for (int m = 0; m < 4; ++m)
    #pragma unroll
    for (int n = 0; n < 4; ++n) acc[m][n] = zero;
  f32x4 rA[4][2], rB[4][2];
  const u16* Ab = (const u16*)A_;
  const u16* Bb = (const u16*)B_;
  const float* Af = (const float*)A_;
  const float* Bf = (const float*)B_;
  // ---- prologue: stage tile 0 into buf 0
  if (!A_F32){
    #pragma unroll
    for (int p = 0; p < 4; ++p)
      gl_lds16(Ab + (size_t)(bm * 128 + srow[p]) * K + scol[p], &As[0][sdst[p]]);
  }
  if (!B_F32){
    #pragma unroll
    for (int p = 0; p < 4; ++p)
      gl_lds16(Bb + (size_t)(bn * 128 + srow[p]) * K + scol[p], &Bs[0][sdst[p]]);
  }
  if (A_F32){
    #pragma unroll
    for (int p = 0; p < 4; ++p){
      const float* src = Af + (size_t)(bm * 128 + rrow[p]) * K + rc8[p] * 8;
      rA[p][0] = *(const f32x4*)src;
      rA[p][1] = *(const f32x4*)(src + 4);
    }
    #pragma unroll
    for (int p = 0; p < 4; ++p){
      union { u16 u[8]; i32x4 v; } pk;
      #pragma unroll
      for (int j = 0; j < 4; ++j){ pk.u[j] = f2bf_fast(rA[p][0][j]); pk.u[4 + j] = f2bf_fast(rA[p][1][j]); }
      *(i32x4*)&As[0][swz(rrow[p], rc8[p] * 16)] = pk.v;
    }
  }
  if (B_F32){
    #pragma unroll
    for (int p = 0; p < 4; ++p){
      const float* src = Bf + (size_t)(bn * 128 + rrow[p]) * K + rc8[p] * 8;
      rB[p][0] = *(const f32x4*)src;
      rB[p][1] = *(const f32x4*)(src + 4);
    }
    #pragma unroll
    for (int p = 0; p < 4; ++p){
      union { u16 u[8]; i32x4 v; } pk;
      #pragma unroll
      for (int j = 0; j < 4; ++j){ pk.u[j] = f2bf_fast(rB[p][0][j]); pk.u[4 + j] = f2bf_fast(rB[p][1][j]); }
      *(i32x4*)&Bs[0][swz(rrow[p], rc8[p] * 16)] = pk.v;
    }
  }
  int NT = K >> 6;
  int cur = 0;
  for (int st = 0; st < NT; ++st){
    __syncthreads();   // buf[cur] ready; prev reads of buf[cur^1] done
    int kt1 = (st + 1) * 64;
    int nb = cur ^ 1;
    if (st + 1 < NT){
      if (!A_F32){
        #pragma unroll
        for (int p = 0; p < 4; ++p)
          gl_lds16(Ab + (size_t)(bm * 128 + srow[p]) * K + kt1 + scol[p], &As[nb][sdst[p]]);
      }
      if (!B_F32){
        #pragma unroll
        for (int p = 0; p < 4; ++p)
          gl_lds16(Bb + (size_t)(bn * 128 + srow[p]) * K + kt1 + scol[p], &Bs[nb][sdst[p]]);
      }
      if (A_F32){
        #pragma unroll
        for (int p = 0; p < 4; ++p){
          const float* src = Af + (size_t)(bm * 128 + rrow[p]) * K + kt1 + rc8[p] * 8;
          rA[p][0] = *(const f32x4*)src;
          rA[p][1] = *(const f32x4*)(src + 4);
        }
      }
      if (B_F32){
        #pragma unroll
        for (int p = 0; p < 4; ++p){
          const float* src = Bf + (size_t)(bn * 128 + rrow[p]) * K + kt1 + rc8[p] * 8;
          rB[p][0] = *(const f32x4*)src;
          rB[p][1] = *(const f32x4*)(src + 4);
        }
      }
    }
    // ---- compute on buf[cur]
    #pragma unroll
    for (int kk = 0; kk < 2; ++kk){
      bf16x8 af[4], bfr[4];
      #pragma unroll
      for (int m = 0; m < 4; ++m){
        int row = wr * 64 + m * 16 + c;
        af[m] = *(const bf16x8*)&As[cur][swz(row, kk * 64 + g * 16)];
      }
      #pragma unroll
      for (int n = 0; n < 4; ++n){
        int row = wc * 64 + n * 16 + c;
        bfr[n] = *(const bf16x8*)&Bs[cur][swz(row, kk * 64 + g * 16)];
      }
      #pragma unroll
      for (int m = 0; m < 4; ++m)
        #pragma unroll
        for (int n = 0; n < 4; ++n)
          acc[m][n] = __builtin_amdgcn_mfma_f32_16x16x32_bf16(af[m], bfr[n], acc[m][n], 0, 0, 0);
    }
    // ---- late ds_write of the f32-path tile
    if (st + 1 < NT){
      if (A_F32){
        #pragma unroll
        for (int p = 0; p < 4; ++p){
          union { u16 u[8]; i32x4 v; } pk;
          #pragma unroll
          for (int j = 0; j < 4; ++j){ pk.u[j] = f2bf_fast(rA[p][0][j]); pk.u[4 + j] = f2bf_fast(rA[p][1][j]); }
          *(i32x4*)&As[nb][swz(rrow[p], rc8[p] * 16)] = pk.v;
        }
      }
      if (B_F32){
        #pragma unroll
        for (int p = 0; p < 4; ++p){
          union { u16 u[8]; i32x4 v; } pk;
          #pragma unroll
          for (int j = 0; j < 4; ++j){ pk.u[j] = f2bf_fast(rB[p][0][j]); pk.u[4 + j] = f2bf_fast(rB[p][1][j]); }
          *(i32x4*)&Bs[nb][swz(rrow[p], rc8[p] * 16)] = pk.v;
        }
      }
    }
    cur ^= 1;
  }
  #pragma unroll
  for (int m = 0; m < 4; ++m)
    #pragma unroll
    for (int n = 0; n < 4; ++n)
      #pragma unroll
      for (int r = 0; r < 4; ++r){
        int row = bm * 128 + wr * 64 + m * 16 + g * 4 + r;
        int col = bn * 128 + wc * 64 + n * 16 + c;
        float v = acc[m][n][r];
        if (EPI == 0){
          int t = row >> 3, b = row & 7, hh = col >> 6, dd = col & 63;
          ((u16*)Cv)[(((size_t)(b * H_ + hh)) * T_ + t) * HD_ + dd] = f2bf(v);
        } else {
          ((float*)Cv)[(size_t)row * N + col] = v + bias[col];
        }
      }
}

// ---------------- u^T = B_h^T q^T; 4 waves/block, wave w owns one 64-t tile ----------------
__global__ __launch_bounds__(256) void k_u(const u16* __restrict__ qb, const u16* __restrict__ Bt,
                                           u16* __restrict__ ubt, float* __restrict__ qsq){
  int blk = (int)blockIdx.x;            // 512 blocks
  int bh = blk >> 2;
  int w = threadIdx.x >> 6;
  int tt = (blk & 3) * 4 + w;
  int h = bh & 15, t0 = tt * 64;
  int lane = threadIdx.x & 63, g = lane >> 4, c = lane & 15;
  const float QS_SCALE = 0.125f * 1.44269504088896340736f;
  bf16x8 af[4][2], bq[4][2];
  #pragma unroll
  for (int mf = 0; mf < 4; ++mf)
    #pragma unroll
    for (int kk = 0; kk < 2; ++kk)
      af[mf][kk] = *(const bf16x8*)(Bt + ((size_t)(h * 64 + mf * 16 + c)) * 64 + kk * 32 + g * 8);
  #pragma unroll
  for (int nf = 0; nf < 4; ++nf)
    #pragma unroll
    for (int kk = 0; kk < 2; ++kk)
      bq[nf][kk] = *(const bf16x8*)(qb + ((size_t)(bh * 1024 + t0 + nf * 16 + c)) * 64 + kk * 32 + g * 8);
  // q_sq from the same bf16 q; prescaled by 0.125*log2(e)
  #pragma unroll
  for (int nf = 0; nf < 4; ++nf){
    float ss = 0.f;
    #pragma unroll
    for (int kk = 0; kk < 2; ++kk)
      #pragma unroll
      for (int j = 0; j < 8; ++j){ float f = bf2f((u16)bq[nf][kk][j]); ss = fmaf(f, f, ss); }
    ss += __shfl_xor(ss, 16);
    ss += __shfl_xor(ss, 32);
    if (lane < 16) qsq[(size_t)bh * 1024 + t0 + nf * 16 + lane] = ss * QS_SCALE;
  }
  f32x4 zero = {0.f, 0.f, 0.f, 0.f};
  f32x4 acc[4][4];
  #pragma unroll
  for (int mf = 0; mf < 4; ++mf)
    #pragma unroll
    for (int nf = 0; nf < 4; ++nf) acc[mf][nf] = zero;
  #pragma unroll
  for (int kk = 0; kk < 2; ++kk)
    #pragma unroll
    for (int mf = 0; mf < 4; ++mf)
      #pragma unroll
      for (int nf = 0; nf < 4; ++nf)
        acc[mf][nf] = __builtin_amdgcn_mfma_f32_16x16x32_bf16(af[mf][kk], bq[nf][kk], acc[mf][nf], 0, 0, 0);
  #pragma unroll
  for (int mf = 0; mf < 4; ++mf)
    #pragma unroll
    for (int nf = 0; nf < 4; ++nf)
      #pragma unroll
      for (int r = 0; r < 4; ++r)
        ubt[((size_t)(bh * 64 + mf * 16 + g * 4 + r)) * 1024 + t0 + nf * 16 + c] = f2bf(acc[mf][nf][r]);
}

// ---------------- L2 attention: TBLK=256, 8 waves x 32 t, dbuf gl_lds, m97 schedule ----------------
// Same per-wave math as r10 (proven); 8 waves share each 64-s K/U tile so per-wave
// staging halves and per-CU round count halves (barrier stalls amortize 2x).
__global__ __launch_bounds__(512, 2) void k_attn(const u16* __restrict__ qb, const u16* __restrict__ ubt,
                                                 const float* __restrict__ qsq, u16* __restrict__ obm){
  int i = (int)blockIdx.x;              // 512 blocks
  // XCD grouping: XCD (i&7) owns bh in [16*(i&7), ...+16), 4 t-tiles each.
  int bh = ((i & 7) << 4) + (i >> 5);
  int tt = (i >> 3) & 3;
  int b = bh >> 4, h = bh & 15;
  int tid = threadIdx.x, w = tid >> 6, lane = tid & 63;
  int lo = lane & 31, hi = lane >> 5;
  __shared__ u16 Kl[2][64 * 64];
  __shared__ u16 Ul[2][64 * 64];
  __shared__ float Qs[1024];
  const float C1 = 0.25f * 1.44269504088896340736f;
  int t0 = tt * 256 + w * 32;
  const u16* qbh = qb + (size_t)bh * 65536;    // [t][64]
  const u16* ubh = ubt + (size_t)bh * 65536;   // [e][1024]
  const float* qsb = qsq + (size_t)bh * 1024;
  // stage the whole scaled-qsq panel once (4KB, 512 thr x 2 floats)
  *(f32x2*)&Qs[tid * 2] = *(const f32x2*)(qsb + tid * 2);
  // Q B-fragment (col=t=lo, k=d): 4 K=16 slices
  bf16x8 qB[4];
  #pragma unroll
  for (int kd = 0; kd < 4; ++kd)
    qB[kd] = *(const bf16x8*)(qbh + (t0 + lo) * 64 + kd * 16 + hi * 8);
  f32x16 o0 = {0,0,0,0,0,0,0,0,0,0,0,0,0,0,0,0};
  f32x16 o1 = {0,0,0,0,0,0,0,0,0,0,0,0,0,0,0,0};
  const f32x16 zero16 = {0,0,0,0,0,0,0,0,0,0,0,0,0,0,0,0};
  float l_c = 0.f;
  // gload slot: one call per operand per wave; slot = tid -> row=tid>>3, c8=tid&7
  int r0 = tid >> 3, sc0 = ((tid & 7) ^ (r0 & 7)) * 8;   // pre-swizzled source chunk
  int d0 = w * 512;                                      // wave-uniform dest base (u16)
  // prologue: issue tile-0 loads into buf 0
  gl_lds16(qbh + r0 * 64 + sc0, &Kl[0][d0]);
  gl_lds16(ubh + (size_t)r0 * 1024 + sc0, &Ul[0][d0]);
  int cur = 0;
  for (int st = 0; st < 16; ++st){
    int s0 = st * 64;
    __syncthreads();   // drains vmcnt(0): buf[cur] landed; all waves past buf[cur^1] reads
    if (st < 15){
      int s1 = s0 + 64;
      int nb = cur ^ 1;
      gl_lds16(qbh + (s1 + r0) * 64 + sc0, &Kl[nb][d0]);
      gl_lds16(ubh + (size_t)r0 * 1024 + s1 + sc0, &Ul[nb][d0]);
    }
    const u16* Kc = &Kl[cur][0];
    const u16* Uc = &Ul[cur][0];
    #pragma unroll
    for (int ts = 0; ts < 2; ++ts){
      f32x16 sf = zero16;
      __builtin_amdgcn_s_setprio(1);
      #pragma unroll
      for (int kd = 0; kd < 4; ++kd){
        bf16x8 kA = *(const bf16x8*)&Kc[swz(ts * 32 + lo, kd * 32 + hi * 16)];
        sf = __builtin_amdgcn_mfma_f32_32x32x16_bf16(kA, qB[kd], sf, 0, 0, 0);
      }
      __builtin_amdgcn_s_setprio(0);
      f32x4 qs_[4];
      #pragma unroll
      for (int q = 0; q < 4; ++q)
        qs_[q] = *(const f32x4*)&Qs[s0 + ts * 32 + q * 8 + hi * 4];
      float p[16];
      #pragma unroll
      for (int r = 0; r < 16; ++r)
        p[r] = exp2_raw(fmaf(sf[r], C1, -qs_[r >> 2][r & 3]));
      float sA = ((p[0] + p[1]) + (p[2] + p[3])) + ((p[4] + p[5]) + (p[6] + p[7]));
      float sB = ((p[8] + p[9]) + (p[10] + p[11])) + ((p[12] + p[13]) + (p[14] + p[15]));
      l_c += sA + sB;
      u32 W[8];
      #pragma unroll
      for (int q = 0; q < 8; ++q)
        W[q] = ((u32)f2bf_fast(p[2 * q + 1]) << 16) | (u32)f2bf_fast(p[2 * q]);
      // PV for this ts: k-slices m_g = ts*2 + {0,1}
      #pragma unroll
      for (int ml = 0; ml < 2; ++ml){
        int m_g = ts * 2 + ml;
        int base = ml * 4;
        i32x2 sw0 = __builtin_amdgcn_permlane32_swap((int)W[base + 0], (int)W[base + 2], false, false);
        i32x2 sw1 = __builtin_amdgcn_permlane32_swap((int)W[base + 1], (int)W[base + 3], false, false);
        union { u32 wd[4]; bf16x8 v; } pa;
        pa.wd[0] = (u32)sw0[0]; pa.wd[1] = (u32)sw1[0]; pa.wd[2] = (u32)sw0[1]; pa.wd[3] = (u32)sw1[1];
        bf16x8 u0 = *(const bf16x8*)&Uc[swz(lo, m_g * 32 + hi * 16)];
        bf16x8 u1 = *(const bf16x8*)&Uc[swz(32 + lo, m_g * 32 + hi * 16)];
        __builtin_amdgcn_s_setprio(1);
        o0 = __builtin_amdgcn_mfma_f32_32x32x16_bf16(pa.v, u0, o0, 0, 0, 0);
        o1 = __builtin_amdgcn_mfma_f32_32x32x16_bf16(pa.v, u1, o1, 0, 0, 0);
        __builtin_amdgcn_s_setprio(0);
      }
    }
    cur ^= 1;
  }
  // l: combine the two hi-halves; lane j then holds l for t = j&31
  l_c += __shfl_xor(l_c, 32);
  float inv = 1.0f / l_c;
  #pragma unroll
  for (int r = 0; r < 16; ++r){
    int tr = (r & 3) + 8 * (r >> 2) + 4 * hi;
    float invr = __shfl(inv, tr);
    size_t rowb = ((size_t)((t0 + tr) * 8 + b)) * 1024 + h * 64;
    obm[rowb + lo] = f2bf(o0[r] * invr);
    obm[rowb + 32 + lo] = f2bf(o1[r] * invr);
  }
}

extern "C" void kernel_launch(void* const* d_in, const int* in_sizes, int n_in,
                              void* d_out, int out_size, void* d_ws, size_t ws_size,
                              hipStream_t stream) {
  const float* x   = (const float*)d_in[0];
  const float* qw  = (const float*)d_in[1];
  const float* vw  = (const float*)d_in[2];
  const float* ow  = (const float*)d_in[3];
  const float* ob_bias = (const float*)d_in[4];
  float* out = (float*)d_out;

  // d_out (32 MiB) doubles as scratch:
  //  - Bp partials (2 MiB) at d_out front, consumed by k_bred before GEMM1 writes qb there
  //  - qb (16 MiB) + ubt (16 MiB) fill it afterwards; all dead before GEMM2 writes `out`.
  float* Bp = (float*)d_out;
  u16* qb  = (u16*)d_out;                                     // [bh][t][d]  16 MiB
  u16* ubt = (u16*)((char*)d_out + (size_t)16 * 1024 * 1024); // [bh][d][t]  16 MiB

  char* ws = (char*)d_ws;
  size_t off = 0;
  auto alloc = [&](size_t bytes) -> void* {
    void* p = ws + off;
    off += (bytes + 255) & ~(size_t)255;
    return p;
  };
  u16*   wqt = (u16*)  alloc((size_t)1024 * 1024 * 2);   // Wq^T bf16 [n][m]   2 MiB
  u16*   obm = (u16*)  alloc((size_t)8192 * 1024 * 2);   // attn out bf16     16 MiB
  float* qsq = (float*)alloc((size_t)128 * 1024 * 4);    // scaled |q|^2     0.5 MiB
  u16*   Bt  = (u16*)  alloc((size_t)16 * 64 * 64 * 2);  // B_h^T bf16      0.125 MiB

  k_pre<<<384, 256, 0, stream>>>(qw, vw, Bp, qw, wqt);
  k_bred<<<256, 256, 0, stream>>>(Bp, Bt);
  // GEMM1: q = x @ Wq  (A = x f32 T14 reg-path, B = Wq^T bf16 gl_lds; dbuf) -> qb scatter
  k_gemm<1, 0, 0><<<512, 256, 0, stream>>>(x, wqt, qb, nullptr, 8192, 1024, 1024);
  k_u<<<512, 256, 0, stream>>>(qb, Bt, ubt, qsq);
  k_attn<<<512, 512, 0, stream>>>(qb, ubt, qsq, obm);
  // GEMM2: out = obm @ out_w^T + b  (A = obm bf16 gl_lds, B = out_w f32 T14 reg-path; dbuf)
  k_gemm<0, 1, 1><<<512, 256, 0, stream>>>(obm, ow, out, ob_bias, 8192, 1024, 1024);
}